// Round 10
// baseline (161.345 us; speedup 1.0000x reference)
//
#include <hip/hip_runtime.h>
#include <hip/hip_bf16.h>

// Raindrop forward, MI355X. B=64 T=128 S=64 O=4 E=64 P=16 A=10 OUT=128.
//  - temporal attention collapsed: (Q K^T) W_s = Q (W_s^T K)  -> no TxT matrix
//  - alpha decomposition: alpha[i][j] = relu(hm10[i]*battn[j] + h[i].v_t + s_t)
//  - k_scale folded into k_main (adjnum f32 prefetch * 1/masksum -> bf16 LDS)
//  - k_main epilogue: h2 -> LDS bounce -> coalesced uint4 stores
//  - k_attn: bf16 PE (peh) -> half the PE traffic
// ws floats: PE(unused) | bidir | masksumInv | adjnum | brp[16] | sT[8192]
// ws bytes @: WrT 1638464 | catx 1642560 | PEh 1644608 | Hh 3479616

typedef unsigned short u16;
typedef unsigned int u32;
typedef __attribute__((ext_vector_type(8))) short short8;
typedef __attribute__((ext_vector_type(4))) float f32x4;

#define OFF_PE    0
#define OFF_BIDIR 131072
#define OFF_MS    135168
#define OFF_ADJ   139264
#define OFF_BRP   401408
#define OFF_ST    401424
#define BOFF_WRT  1638464u
#define BOFF_CATX 1642560u
#define BOFF_PEH  1644608u
#define BOFF_V    2431040u
#define BOFF_HH   3479616u

__device__ __forceinline__ u16 f2bf(float f){
  __hip_bfloat16 h = __float2bfloat16(f);
  union { __hip_bfloat16 h; u16 u; } v; v.h = h; return v.u;
}
__device__ __forceinline__ u32 pk2bf(float lo, float hi){
  __hip_bfloat162 h = __float22bfloat162_rn(float2{lo, hi});
  union { __hip_bfloat162 h; u32 u; } v; v.h = h; return v.u;
}
__device__ __forceinline__ float bf2f(u16 h){
  union { u32 u; float f; } v; v.u = ((u32)h) << 16; return v.f;
}

// ---------------- K0: peh/v/sT, bidir(x4), WrT/brp/catx, masksumInv ----------------
__global__ void k_pre(const float* __restrict__ times, const float* __restrict__ mask,
                      const float* __restrict__ Wb, const float* __restrict__ Wrecv,
                      const float* __restrict__ brecv, const float* __restrict__ battn,
                      float* __restrict__ ws_f, char* __restrict__ ws_b) {
  __shared__ float peL[32][17];
  __shared__ float wpe[64][17];
  __shared__ float pm[4][64];
  const int blk = blockIdx.x, tid = threadIdx.x;
  u16* wrt  = (u16*)(ws_b + BOFF_WRT);
  u16* catx = (u16*)(ws_b + BOFF_CATX);
  u16* peh  = (u16*)(ws_b + BOFF_PEH);
  u16* vv   = (u16*)(ws_b + BOFF_V);
  float* ST = ws_f + OFF_ST;
  if (blk < 256) {                     // PE (bf16) + v_t + s_t for 32 bt rows
    #pragma unroll
    for (int r = 0; r < 2; ++r) {
      int id = blk * 512 + r * 256 + tid;
      int bt = id >> 4, k = id & 15;
      float tv = times[bt];
      int kk = k & 7;
      float fr = expf(-(float)kk * 1.1512925465f); // ln(1e4)/8
      float ang = tv * fr;
      float v = (k < 8) ? sinf(ang) : cosf(ang);
      peh[id] = f2bf(v);
      peL[r*16 + (tid >> 4)][k] = v;
    }
    #pragma unroll
    for (int q = 0; q < 4; ++q) {
      int idx = q * 256 + tid;
      wpe[idx >> 4][idx & 15] = Wrecv[(idx >> 4)*26 + 10 + (idx & 15)];
    }
    __syncthreads();
    {
      int btl = tid >> 3, e0 = (tid & 7) * 8;
      float acc[8];
      #pragma unroll
      for (int i = 0; i < 8; ++i) acc[i] = 0.f;
      #pragma unroll
      for (int k = 0; k < 16; ++k) {
        float p = peL[btl][k];
        #pragma unroll
        for (int i = 0; i < 8; ++i) acc[i] += wpe[e0 + i][k] * p;
      }
      u32* dst = (u32*)&vv[(blk*32 + btl)*64 + e0];
      #pragma unroll
      for (int p = 0; p < 4; ++p) dst[p] = pk2bf(acc[2*p], acc[2*p+1]);
      if (tid < 32) {
        float s = 0.f;
        #pragma unroll
        for (int k = 0; k < 16; ++k) s += brecv[10 + k] * peL[tid][k];
        ST[blk*32 + tid] = s;
      }
    }
  } else if (blk < 260) {              // bidir = Wb @ Wb^T (4 blocks)
    float* bidir = ws_f + OFF_BIDIR;
    int q = blk - 256;
    for (int rr = 0; rr < 4; ++rr) {
      int idx = (q*4 + rr) * 256 + tid;
      int i = idx >> 6, j = idx & 63;
      float acc = 0.f;
      for (int e = 0; e < 64; ++e) acc += Wb[i*64+e] * Wb[j*64+e];
      bidir[idx] = acc;
    }
  } else if (blk == 260) {             // WrT, brp (pad16), catx
    for (int r = 0; r < 8; ++r) {
      int idx = r * 256 + tid;
      int d = idx >> 6, e = idx & 63;
      wrt[idx] = (d < 26) ? f2bf(Wrecv[e*26 + d]) : (u16)0;
    }
    if (tid < 16) ws_f[OFF_BRP + tid] = (tid < 10) ? brecv[tid] : 0.f;
    #pragma unroll
    for (int i = 0; i < 4; ++i) {
      int idx = i * 256 + tid;
      int j = idx >> 4, d = idx & 15;
      catx[idx] = (d < 10) ? f2bf(battn[j*10 + d]) : ((d == 10) ? f2bf(1.f) : (u16)0);
    }
  } else {                             // masksumInv[b][i]
    int b = blk - 261;
    int i = tid & 63, q = tid >> 6;
    float s = 0.f;
    for (int t = q*32; t < q*32 + 32; ++t) s += mask[(b*128 + t)*64 + i];
    pm[q][i] = s;
    __syncthreads();
    if (tid < 64)
      (ws_f + OFF_MS)[b*64 + tid] =
          1.0f / (pm[0][tid] + pm[1][tid] + pm[2][tid] + pm[3][tid]);
  }
}

// ---------------- K1: adj2 numerator (sum_t alpha) ----------------
__global__ __launch_bounds__(256)
void k_adj(const float* __restrict__ x, const float* __restrict__ mask,
           const float* __restrict__ Wobs, float* __restrict__ ws_f,
           const char* __restrict__ ws_b) {
  __shared__ __align__(16) u16 hA[64][72];
  __shared__ __align__(16) u16 hmA[64][24];

  const int tid = threadIdx.x;
  const int b = blockIdx.y, tc = blockIdx.x;
  const int w = tid >> 6, l = tid & 63, lr = l & 15, lq = l >> 4, kb = lq * 8;
  const u16* wrt  = (const u16*)(ws_b + BOFF_WRT);
  const u16* catx = (const u16*)(ws_b + BOFF_CATX);
  const u16* vv   = (const u16*)(ws_b + BOFF_V);
  const float* brp = ws_f + OFF_BRP;
  const float* ST = ws_f + OFF_ST;
  float* adj = ws_f + OFF_ADJ;

  const short8 z8 = (short8){0,0,0,0,0,0,0,0};
  const bool lowk = (lq < 2);
  short8 w0 = z8, w1 = z8;
  if (lr < 10) {
    const u16* wr = wrt + lr * 64;
    w0 = *(const short8*)&wr[kb];
    w1 = *(const short8*)&wr[32 + kb];
  }
  short8 bc[4];
  #pragma unroll
  for (int n = 0; n < 4; ++n)
    bc[n] = lowk ? *(const short8*)&catx[(16*n + lr)*16 + lq*8] : z8;
  float4 bv = *(const float4*)&brp[lq*4];

  f32x4 asum[4];
  #pragma unroll
  for (int n = 0; n < 4; ++n) asum[n] = (f32x4){0.f,0.f,0.f,0.f};

  const int e4 = tid & 15, sg = tid >> 4;

  for (int tt = 0; tt < 8; ++tt) {
    int t = tc * 8 + tt;
    int base = b * 128 + t;
    short8 av0 = z8, av1 = z8;
    if (lr == 10) {
      av0 = *(const short8*)&vv[base*64 + kb];
      av1 = *(const short8*)&vv[base*64 + 32 + kb];
    }
    float st = ST[base];
    {
      float4 mk4 = *(const float4*)&mask[base*64 + sg*4];
      float mks[4] = {mk4.x, mk4.y, mk4.z, mk4.w};
      #pragma unroll
      for (int si = 0; si < 4; ++si) {
        int s = sg*4 + si;
        float4 xv = *(const float4*)&x[base*256 + s*4];
        float xo[4] = {xv.x, xv.y, xv.z, xv.w};
        float ax = 0.f, ay = 0.f, az = 0.f, aw = 0.f;
        #pragma unroll
        for (int o = 0; o < 4; ++o) {
          float4 wv = *(const float4*)&Wobs[(s*4+o)*64 + e4*4];
          ax += xo[o]*wv.x; ay += xo[o]*wv.y; az += xo[o]*wv.z; aw += xo[o]*wv.w;
        }
        float mk = mks[si];
        uint2 p;
        p.x = pk2bf(fmaxf(ax,0.f)*mk, fmaxf(ay,0.f)*mk);
        p.y = pk2bf(fmaxf(az,0.f)*mk, fmaxf(aw,0.f)*mk);
        *(uint2*)&hA[s][e4*4] = p;
      }
    }
    __syncthreads();
    { // P1
      short8 a0 = (lr < 10) ? w0 : av0;
      short8 a1 = (lr < 10) ? w1 : av1;
      f32x4 acc = (f32x4){0.f,0.f,0.f,0.f};
      short8 b0 = *(const short8*)&hA[16*w + lr][kb];
      short8 b1 = *(const short8*)&hA[16*w + lr][32 + kb];
      acc = __builtin_amdgcn_mfma_f32_16x16x32_bf16(a0, b0, acc, 0, 0, 0);
      acc = __builtin_amdgcn_mfma_f32_16x16x32_bf16(a1, b1, acc, 0, 0, 0);
      uint2 qq;
      qq.x = pk2bf(acc[0]+bv.x, acc[1]+bv.y);
      qq.y = pk2bf(acc[2]+bv.z, acc[3]+bv.w);
      *(uint2*)&hmA[16*w + lr][lq*4] = qq;
    }
    __syncthreads();
    { // P2
      short8 am = lowk ? *(const short8*)&hmA[16*w + lr][lq*8] : z8;
      #pragma unroll
      for (int n = 0; n < 4; ++n) {
        f32x4 z = (f32x4){st, st, st, st};
        z = __builtin_amdgcn_mfma_f32_16x16x32_bf16(am, bc[n], z, 0, 0, 0);
        #pragma unroll
        for (int reg = 0; reg < 4; ++reg) asum[n][reg] += fmaxf(z[reg], 0.f);
      }
    }
    __syncthreads();
  }
  #pragma unroll
  for (int n = 0; n < 4; ++n) {
    #pragma unroll
    for (int reg = 0; reg < 4; ++reg) {
      int i = 16*w + lq*4 + reg, j = 16*n + lr;
      atomicAdd(&adj[((size_t)b << 12) + (i << 6) + j], asum[n][reg]);
    }
  }
}

// ---------------- K2: full per-(b,t) chain -> Hh bf16 (1 t/block) ----------------
__global__ __launch_bounds__(256, 4)
void k_main(const float* __restrict__ x, const float* __restrict__ mask,
            const float* __restrict__ Wobs, const float* __restrict__ ws_f,
            const char* __restrict__ ws_b, u16* __restrict__ Hh) {
  __shared__ __align__(16) char smem[36864];
  u16 (*hA)[72]  = (u16 (*)[72])(smem);           // h [s][e]; later h1T [e][i]
  u16 (*hT)[72]  = (u16 (*)[72])(smem + 9216);    // h^T [e][s]; later h2L [i][e]
  u16 (*wA)[72]  = (u16 (*)[72])(smem + 18432);   // w1 [i][j]
  u16 (*hmA)[24] = (u16 (*)[24])(smem + 27648);   // hmx [s][dx]  (dead after P2)
  u16 (*adjS)[72]= (u16 (*)[72])(smem + 27648);   // overlay, staged in P3
  u16 (*h2L)[72] = (u16 (*)[72])(smem + 9216);    // epilogue bounce (over hT)

  const int tid = threadIdx.x;
  const int t = blockIdx.x, b = blockIdx.y;
  const int w = tid >> 6, l = tid & 63, lr = l & 15, lq = l >> 4, kb = lq * 8;
  const int base = b * 128 + t;
  const u16* wrt  = (const u16*)(ws_b + BOFF_WRT);
  const u16* catx = (const u16*)(ws_b + BOFF_CATX);
  const u16* vv   = (const u16*)(ws_b + BOFF_V);
  const float* bidirG = ws_f + OFF_BIDIR;
  const float* brp = ws_f + OFF_BRP;
  const float* msInv = ws_f + OFF_MS + b * 64;
  const int i0 = 16*w + lq*4;
  const short8 z8 = (short8){0,0,0,0,0,0,0,0};
  const bool lowk = (lq < 2);

  // ---- prefetches: long-latency loads issued before any compute ----
  const float4* agf = (const float4*)(ws_f + OFF_ADJ + (size_t)b * 4096);
  float4 ga0 = agf[tid], ga1 = agf[tid + 256], ga2 = agf[tid + 512], ga3 = agf[tid + 768];
  float msr0 = msInv[(tid >> 4)], msr1 = msInv[(tid >> 4) + 16],
        msr2 = msInv[(tid >> 4) + 32], msr3 = msInv[(tid >> 4) + 48];
  short8 w0 = z8, w1 = z8;
  if (lr < 10) {
    const u16* wr = wrt + lr * 64;
    w0 = *(const short8*)&wr[kb];
    w1 = *(const short8*)&wr[32 + kb];
  }
  short8 av0 = z8, av1 = z8;
  if (lr == 10) {
    av0 = *(const short8*)&vv[base*64 + kb];
    av1 = *(const short8*)&vv[base*64 + 32 + kb];
  }
  short8 bc[4];
  #pragma unroll
  for (int n = 0; n < 4; ++n)
    bc[n] = lowk ? *(const short8*)&catx[(16*n + lr)*16 + lq*8] : z8;
  float4 bv = *(const float4*)&brp[lq*4];
  const float st = (ws_f + OFF_ST)[base];

  { // P0: h build (direct x/mask loads)
    const int e4 = tid & 15, sg = tid >> 4;
    float4 mk4 = *(const float4*)&mask[base*64 + sg*4];
    float mks[4] = {mk4.x, mk4.y, mk4.z, mk4.w};
    #pragma unroll
    for (int si = 0; si < 4; ++si) {
      int s = sg*4 + si;
      float4 xv = *(const float4*)&x[base*256 + s*4];
      float xo[4] = {xv.x, xv.y, xv.z, xv.w};
      float ax = 0.f, ay = 0.f, az = 0.f, aw = 0.f;
      #pragma unroll
      for (int o = 0; o < 4; ++o) {
        float4 wv = *(const float4*)&Wobs[(s*4+o)*64 + e4*4];
        ax += xo[o]*wv.x; ay += xo[o]*wv.y; az += xo[o]*wv.z; aw += xo[o]*wv.w;
      }
      float mk = mks[si];
      uint2 p;
      p.x = pk2bf(fmaxf(ax,0.f)*mk, fmaxf(ay,0.f)*mk);
      p.y = pk2bf(fmaxf(az,0.f)*mk, fmaxf(aw,0.f)*mk);
      *(uint2*)&hA[s][e4*4] = p;
    }
  }
  __syncthreads();

  { // P1: hT rebuild + hmx MFMA
    #pragma unroll
    for (int sp = 0; sp < 8; ++sp) {
      int s = w*16 + sp*2;
      *(u32*)&hT[l][s] = (u32)hA[s][l] | ((u32)hA[s+1][l] << 16);
    }
    short8 a0 = (lr < 10) ? w0 : av0;
    short8 a1 = (lr < 10) ? w1 : av1;
    f32x4 acc = (f32x4){0.f,0.f,0.f,0.f};
    short8 b0 = *(const short8*)&hA[16*w + lr][kb];
    short8 b1 = *(const short8*)&hA[16*w + lr][32 + kb];
    acc = __builtin_amdgcn_mfma_f32_16x16x32_bf16(a0, b0, acc, 0, 0, 0);
    acc = __builtin_amdgcn_mfma_f32_16x16x32_bf16(a1, b1, acc, 0, 0, 0);
    uint2 qq;
    qq.x = pk2bf(acc[0]+bv.x, acc[1]+bv.y);
    qq.y = pk2bf(acc[2]+bv.z, acc[3]+bv.w);
    *(uint2*)&hmA[16*w + lr][lq*4] = qq;
  }
  __syncthreads();

  { // P2: alpha -> w1 (wA)
    short8 am = lowk ? *(const short8*)&hmA[16*w + lr][lq*8] : z8;
    #pragma unroll
    for (int n = 0; n < 4; ++n) {
      f32x4 z = (f32x4){st, st, st, st};
      z = __builtin_amdgcn_mfma_f32_16x16x32_bf16(am, bc[n], z, 0, 0, 0);
      int j = 16*n + lr;
      #pragma unroll
      for (int reg = 0; reg < 4; ++reg) {
        float w1v = fmaxf(z[reg], 0.f) * bidirG[((i0+reg) << 6) + j];
        wA[i0 + reg][j] = f2bf(w1v);
      }
    }
  }
  __syncthreads();

  { // P3: adjS = bf16(adjnum * msInv) -> LDS (overlay); h1 = relu(w1 @ h) -> h1T
    int arow = tid >> 4, acol = (tid & 15) * 4;
    uint2 p;
    p.x = pk2bf(ga0.x*msr0, ga0.y*msr0); p.y = pk2bf(ga0.z*msr0, ga0.w*msr0);
    *(uint2*)&adjS[arow][acol] = p;
    p.x = pk2bf(ga1.x*msr1, ga1.y*msr1); p.y = pk2bf(ga1.z*msr1, ga1.w*msr1);
    *(uint2*)&adjS[arow + 16][acol] = p;
    p.x = pk2bf(ga2.x*msr2, ga2.y*msr2); p.y = pk2bf(ga2.z*msr2, ga2.w*msr2);
    *(uint2*)&adjS[arow + 32][acol] = p;
    p.x = pk2bf(ga3.x*msr3, ga3.y*msr3); p.y = pk2bf(ga3.z*msr3, ga3.w*msr3);
    *(uint2*)&adjS[arow + 48][acol] = p;

    short8 aw0 = *(const short8*)&wA[16*w + lr][kb];
    short8 aw1 = *(const short8*)&wA[16*w + lr][32 + kb];
    #pragma unroll
    for (int n = 0; n < 4; ++n) {
      f32x4 acc = (f32x4){0.f,0.f,0.f,0.f};
      short8 b0 = *(const short8*)&hT[16*n + lr][kb];
      short8 b1 = *(const short8*)&hT[16*n + lr][32 + kb];
      acc = __builtin_amdgcn_mfma_f32_16x16x32_bf16(aw0, b0, acc, 0, 0, 0);
      acc = __builtin_amdgcn_mfma_f32_16x16x32_bf16(aw1, b1, acc, 0, 0, 0);
      int e = 16*n + lr;
      uint2 pp;
      pp.x = pk2bf(fmaxf(acc[0],0.f), fmaxf(acc[1],0.f));
      pp.y = pk2bf(fmaxf(acc[2],0.f), fmaxf(acc[3],0.f));
      *(uint2*)&hA[e][i0] = pp;   // h1T[e][i]
    }
  }
  __syncthreads();

  { // P4: w2 = w1 (.) adjS; h2 = relu(w2 @ h1) -> h2L (LDS bounce)
    int row = 16*w + lr;
    union { short8 v; u16 h[8]; u32 u[4]; } uw0, uw1, ud0, ud1, oa, ob;
    uw0.v = *(const short8*)&wA[row][kb];
    uw1.v = *(const short8*)&wA[row][32 + kb];
    ud0.v = *(const short8*)&adjS[row][kb];
    ud1.v = *(const short8*)&adjS[row][32 + kb];
    #pragma unroll
    for (int k = 0; k < 4; ++k) {
      oa.u[k] = pk2bf(bf2f(uw0.h[2*k])*bf2f(ud0.h[2*k]),
                      bf2f(uw0.h[2*k+1])*bf2f(ud0.h[2*k+1]));
      ob.u[k] = pk2bf(bf2f(uw1.h[2*k])*bf2f(ud1.h[2*k]),
                      bf2f(uw1.h[2*k+1])*bf2f(ud1.h[2*k+1]));
    }
    short8 a20 = oa.v, a21 = ob.v;
    #pragma unroll
    for (int n = 0; n < 4; ++n) {
      f32x4 acc = (f32x4){0.f,0.f,0.f,0.f};
      short8 b0 = *(const short8*)&hA[16*n + lr][kb];      // h1T
      short8 b1 = *(const short8*)&hA[16*n + lr][32 + kb];
      acc = __builtin_amdgcn_mfma_f32_16x16x32_bf16(a20, b0, acc, 0, 0, 0);
      acc = __builtin_amdgcn_mfma_f32_16x16x32_bf16(a21, b1, acc, 0, 0, 0);
      int e = 16*n + lr;
      u32 p0 = pk2bf(fmaxf(acc[0],0.f), fmaxf(acc[1],0.f));
      u32 p1 = pk2bf(fmaxf(acc[2],0.f), fmaxf(acc[3],0.f));
      h2L[i0+0][e] = (u16)p0;
      h2L[i0+1][e] = (u16)(p0 >> 16);
      h2L[i0+2][e] = (u16)p1;
      h2L[i0+3][e] = (u16)(p1 >> 16);
    }
  }
  __syncthreads();

  { // epilogue: coalesced store (4 rows of 128 B per wave)
    int i = tid >> 2, q = tid & 3;
    const uint4* srcv = (const uint4*)&h2L[i][q * 16];
    uint4 v0 = srcv[0], v1 = srcv[1];
    size_t obase = ((size_t)b * 64) * 8192 + (size_t)t * 64;
    uint4* dst = (uint4*)&Hh[obase + (size_t)i * 8192 + q * 16];
    dst[0] = v0; dst[1] = v1;
  }
}

// ---------------- K3: collapsed temporal attention (512 threads) ----------------
#define HTP 82

__global__ __launch_bounds__(512)
void k_attn(const char* __restrict__ ws_b, const u16* __restrict__ Hh,
            const float* __restrict__ Wq, const float* __restrict__ bq,
            const float* __restrict__ Wk, const float* __restrict__ bk,
            const float* __restrict__ Ws, const float* __restrict__ bs,
            const float* __restrict__ Wemb, const float* __restrict__ bemb,
            float* __restrict__ out) {
  __shared__ u16 Ht[128][HTP];
  __shared__ u16 peB[128][18];
  __shared__ float wsL[128];
  __shared__ float pA[6][80];
  __shared__ float pK[8][10];
  __shared__ float qvL[80];
  __shared__ float pC[4][128];
  __shared__ float bb[128];
  __shared__ float red[4];
  __shared__ float cstL, sWL;

  const int tid = threadIdx.x;
  const int s = blockIdx.x, b = blockIdx.y;
  const float scale = 0.111803398875f; // 1/sqrt(80)
  const u16* peh = (const u16*)(ws_b + BOFF_PEH);

  const u16* src = Hh + ((size_t)b * 64 + s) * 8192;
  #pragma unroll
  for (int r = 0; r < 2; ++r) {
    int id = r * 512 + tid;
    int tt = id >> 3, c = (id & 7) * 8;
    uint4 q = *(const uint4*)&src[tt * 64 + c];
    u32* dst = (u32*)&Ht[tt][c];
    dst[0] = q.x; dst[1] = q.y; dst[2] = q.z; dst[3] = q.w;
  }
  #pragma unroll
  for (int r = 0; r < 2; ++r) {
    int id = r * 512 + tid;              // 1024 u32 = 2048 u16 PE values
    u32 pv = ((const u32*)(peh + (size_t)b * 2048))[id];
    *(u32*)&peB[id >> 3][(id & 7) * 2] = pv;
  }
  if (tid < 128) wsL[tid] = Ws[tid];
  __syncthreads();

  // Phase A: hbar partials over 6 t-chunks of ~22
  if (tid < 480) {
    int d = tid % 80, c = tid / 80;
    int t0 = c * 22, t1 = (t0 + 22 > 128) ? 128 : t0 + 22;
    float a0 = 0.f, a1 = 0.f, a2 = 0.f, a3 = 0.f;
    int t = t0;
    if (d < 64) {
      for (; t + 4 <= t1; t += 4) {
        a0 += wsL[t]   * bf2f(Ht[t][d]);
        a1 += wsL[t+1] * bf2f(Ht[t+1][d]);
        a2 += wsL[t+2] * bf2f(Ht[t+2][d]);
        a3 += wsL[t+3] * bf2f(Ht[t+3][d]);
      }
      for (; t < t1; ++t) a0 += wsL[t] * bf2f(Ht[t][d]);
    } else {
      int k = d - 64;
      for (; t + 4 <= t1; t += 4) {
        a0 += wsL[t]   * bf2f(peB[t][k]);
        a1 += wsL[t+1] * bf2f(peB[t+1][k]);
        a2 += wsL[t+2] * bf2f(peB[t+2][k]);
        a3 += wsL[t+3] * bf2f(peB[t+3][k]);
      }
      for (; t < t1; ++t) a0 += wsL[t] * bf2f(peB[t][k]);
    }
    pA[c][d] = (a0 + a1) + (a2 + a3);
  } else if (tid == 480) {
    float a0 = 0.f, a1 = 0.f, a2 = 0.f, a3 = 0.f;
    for (int t = 0; t < 128; t += 4) {
      a0 += wsL[t]; a1 += wsL[t+1]; a2 += wsL[t+2]; a3 += wsL[t+3];
    }
    sWL = (a0 + a1) + (a2 + a3);
  }
  __syncthreads();

  if (tid < 80) {
    int a = tid % 10, c = tid / 10;
    float a0 = 0.f, a1 = 0.f;
    #pragma unroll
    for (int i = 0; i < 10; i += 2) {
      int d = c * 10 + i;
      float h0 = pA[0][d] + pA[1][d] + pA[2][d] + pA[3][d] + pA[4][d] + pA[5][d];
      float h1 = pA[0][d+1] + pA[1][d+1] + pA[2][d+1] + pA[3][d+1] + pA[4][d+1] + pA[5][d+1];
      a0 += h0 * Wk[d * 10 + a];
      a1 += h1 * Wk[(d+1) * 10 + a];
    }
    pK[c][a] = a0 + a1;
  }
  __syncthreads();

  if (tid <= 80) {
    float kt[10];
    #pragma unroll
    for (int a = 0; a < 10; ++a) {
      float acc = sWL * bk[a];
      #pragma unroll
      for (int c = 0; c < 8; ++c) acc += pK[c][a];
      kt[a] = acc;
    }
    if (tid < 80) {
      float a0 = 0.f, a1 = 0.f;
      #pragma unroll
      for (int a = 0; a < 10; a += 2) {
        a0 += Wq[tid * 10 + a] * kt[a];
        a1 += Wq[tid * 10 + a + 1] * kt[a + 1];
      }
      qvL[tid] = a0 + a1;
    } else {
      float cq = 0.f;
      #pragma unroll
      for (int a = 0; a < 10; ++a) cq += bq[a] * kt[a];
      cstL = scale * cq + bs[0];
    }
  }
  __syncthreads();

  // Phase C: beta partials over 4 d-quarters
  {
    int t = tid & 127, q = tid >> 7;
    float a0 = 0.f, a1 = 0.f, a2 = 0.f, a3 = 0.f;
    const u32* row = (const u32*)&Ht[t][0];
    if (q == 0) {
      #pragma unroll
      for (int i = 0; i < 10; i += 2) {
        u32 p0 = row[i], p1 = row[i+1];
        a0 += bf2f((u16)p0) * qvL[2*i]   + bf2f((u16)(p0 >> 16)) * qvL[2*i+1];
        a1 += bf2f((u16)p1) * qvL[2*i+2] + bf2f((u16)(p1 >> 16)) * qvL[2*i+3];
      }
    } else if (q == 1) {
      #pragma unroll
      for (int i = 10; i < 20; i += 2) {
        u32 p0 = row[i], p1 = row[i+1];
        a0 += bf2f((u16)p0) * qvL[2*i]   + bf2f((u16)(p0 >> 16)) * qvL[2*i+1];
        a1 += bf2f((u16)p1) * qvL[2*i+2] + bf2f((u16)(p1 >> 16)) * qvL[2*i+3];
      }
    } else if (q == 2) {
      #pragma unroll
      for (int i = 20; i < 32; i += 4) {
        u32 p0 = row[i], p1 = row[i+1], p2 = row[i+2], p3 = row[i+3];
        a0 += bf2f((u16)p0) * qvL[2*i]   + bf2f((u16)(p0 >> 16)) * qvL[2*i+1];
        a1 += bf2f((u16)p1) * qvL[2*i+2] + bf2f((u16)(p1 >> 16)) * qvL[2*i+3];
        a2 += bf2f((u16)p2) * qvL[2*i+4] + bf2f((u16)(p2 >> 16)) * qvL[2*i+5];
        a3 += bf2f((u16)p3) * qvL[2*i+6] + bf2f((u16)(p3 >> 16)) * qvL[2*i+7];
      }
    } else {
      #pragma unroll
      for (int k = 0; k < 16; k += 4) {
        a0 += bf2f(peB[t][k])   * qvL[64 + k];
        a1 += bf2f(peB[t][k+1]) * qvL[65 + k];
        a2 += bf2f(peB[t][k+2]) * qvL[66 + k];
        a3 += bf2f(peB[t][k+3]) * qvL[67 + k];
      }
    }
    pC[q][t] = (a0 + a1) + (a2 + a3);
  }
  __syncthreads();

  if (tid < 128) {
    float v = scale * (pC[0][tid] + pC[1][tid] + pC[2][tid] + pC[3][tid]) + cstL;
    bb[tid] = v;
    float mm = v;
    #pragma unroll
    for (int off = 32; off; off >>= 1) mm = fmaxf(mm, __shfl_xor(mm, off));
    if ((tid & 63) == 0) red[tid >> 6] = mm;
  }
  __syncthreads();
  float mx = fmaxf(red[0], red[1]);
  if (tid < 128) {
    float ev = expf(bb[tid] - mx);
    bb[tid] = ev;
    float ss = ev;
    #pragma unroll
    for (int off = 32; off; off >>= 1) ss += __shfl_xor(ss, off);
    if ((tid & 63) == 0) red[2 + (tid >> 6)] = ss;
  }
  __syncthreads();

  // Phase E: hout partials (reuse pA), 6 t-chunks
  if (tid < 480) {
    int d = tid % 80, c = tid / 80;
    int t0 = c * 22, t1 = (t0 + 22 > 128) ? 128 : t0 + 22;
    float a0 = 0.f, a1 = 0.f, a2 = 0.f, a3 = 0.f;
    int t = t0;
    if (d < 64) {
      for (; t + 4 <= t1; t += 4) {
        a0 += bb[t]   * bf2f(Ht[t][d]);
        a1 += bb[t+1] * bf2f(Ht[t+1][d]);
        a2 += bb[t+2] * bf2f(Ht[t+2][d]);
        a3 += bb[t+3] * bf2f(Ht[t+3][d]);
      }
      for (; t < t1; ++t) a0 += bb[t] * bf2f(Ht[t][d]);
    } else {
      int k = d - 64;
      for (; t + 4 <= t1; t += 4) {
        a0 += bb[t]   * bf2f(peB[t][k]);
        a1 += bb[t+1] * bf2f(peB[t+1][k]);
        a2 += bb[t+2] * bf2f(peB[t+2][k]);
        a3 += bb[t+3] * bf2f(peB[t+3][k]);
      }
      for (; t < t1; ++t) a0 += bb[t] * bf2f(peB[t][k]);
    }
    pA[c][d] = (a0 + a1) + (a2 + a3);
  }
  __syncthreads();

  // Phase F: out partials over 4 d-chunks of 20 (reuse pC)
  {
    int o = tid & 127, q = tid >> 7;
    int d0 = q * 20;
    float a0 = 0.f, a1 = 0.f, a2 = 0.f, a3 = 0.f;
    #pragma unroll
    for (int i = 0; i < 20; i += 4) {
      int d = d0 + i;
      float h0 = pA[0][d]   + pA[1][d]   + pA[2][d]   + pA[3][d]   + pA[4][d]   + pA[5][d];
      float h1 = pA[0][d+1] + pA[1][d+1] + pA[2][d+1] + pA[3][d+1] + pA[4][d+1] + pA[5][d+1];
      float h2 = pA[0][d+2] + pA[1][d+2] + pA[2][d+2] + pA[3][d+2] + pA[4][d+2] + pA[5][d+2];
      float h3 = pA[0][d+3] + pA[1][d+3] + pA[2][d+3] + pA[3][d+3] + pA[4][d+3] + pA[5][d+3];
      a0 += h0 * Wemb[d * 128 + o];
      a1 += h1 * Wemb[(d+1) * 128 + o];
      a2 += h2 * Wemb[(d+2) * 128 + o];
      a3 += h3 * Wemb[(d+3) * 128 + o];
    }
    pC[q][o] = (a0 + a1) + (a2 + a3);
  }
  __syncthreads();
  if (tid < 128) {
    float rdenom = 1.0f / (red[2] + red[3]);
    out[(((size_t)b * 64 + s) << 7) + tid] =
        bemb[tid] + (pC[0][tid] + pC[1][tid] + pC[2][tid] + pC[3][tid]) * rdenom;
  }
}

extern "C" void kernel_launch(void* const* d_in, const int* in_sizes, int n_in,
                              void* d_out, int out_size, void* d_ws, size_t ws_size,
                              hipStream_t stream) {
  (void)in_sizes; (void)n_in; (void)out_size; (void)ws_size;
  const float* x     = (const float*)d_in[0];
  const float* times = (const float*)d_in[1];
  const float* mask  = (const float*)d_in[2];
  const float* Wobs  = (const float*)d_in[3];
  const float* Wattn = (const float*)d_in[4];
  const float* Wrecv = (const float*)d_in[5];
  const float* brecv = (const float*)d_in[6];
  const float* Wb    = (const float*)d_in[7];
  const float* Wq    = (const float*)d_in[8];
  const float* bq    = (const float*)d_in[9];
  const float* Wk    = (const float*)d_in[10];
  const float* bk    = (const float*)d_in[11];
  const float* Ws    = (const float*)d_in[12];
  const float* bs    = (const float*)d_in[13];
  const float* Wemb  = (const float*)d_in[14];
  const float* bemb  = (const float*)d_in[15];
  float* out = (float*)d_out;
  float* ws_f = (float*)d_ws;
  char* ws_b = (char*)d_ws;
  u16* Hh = (u16*)(ws_b + BOFF_HH);

  hipMemsetAsync(ws_b + (size_t)OFF_ADJ * 4, 0, (size_t)64 * 64 * 64 * 4, stream);
  k_pre<<<325, 256, 0, stream>>>(times, mask, Wb, Wrecv, brecv, Wattn, ws_f, ws_b);
  k_adj<<<dim3(16, 64), 256, 0, stream>>>(x, mask, Wobs, ws_f, ws_b);
  k_main<<<dim3(128, 64), 256, 0, stream>>>(x, mask, Wobs, ws_f, ws_b, Hh);
  k_attn<<<dim3(64, 64), 512, 0, stream>>>(ws_b, Hh, Wq, bq, Wk, bk, Ws, bs, Wemb, bemb, out);
}

// Round 11
// 149.931 us; speedup vs baseline: 1.0761x; 1.0761x over previous
//
#include <hip/hip_runtime.h>
#include <hip/hip_bf16.h>

// Raindrop forward, MI355X. B=64 T=128 S=64 O=4 E=64 P=16 A=10 OUT=128.
//  - temporal attention collapsed: (Q K^T) W_s = Q (W_s^T K)  -> no TxT matrix
//  - alpha decomposition: alpha[i][j] = relu(hm10[i]*battn[j] + h[i].v_t + s_t)
//  - k_main: round-9 structure (bf16 adjS prefetch, direct stores) — r10 fold/bounce reverted
//  - k_attn: bf16 PE (peh); k_pre writes no f32 PE
// ws floats: (unused) | bidir | masksumInv | adjnum | brp[16] | sT[8192]
// ws bytes @: WrT 1638464 | catx 1642560 | PEh 1644608 | adjS 1906752 | V 2431040 | Hh 3479616

typedef unsigned short u16;
typedef unsigned int u32;
typedef __attribute__((ext_vector_type(8))) short short8;
typedef __attribute__((ext_vector_type(4))) float f32x4;

#define OFF_BIDIR 131072
#define OFF_MS    135168
#define OFF_ADJ   139264
#define OFF_BRP   401408
#define OFF_ST    401424
#define BOFF_WRT  1638464u
#define BOFF_CATX 1642560u
#define BOFF_PEH  1644608u
#define BOFF_ADJS 1906752u
#define BOFF_V    2431040u
#define BOFF_HH   3479616u

__device__ __forceinline__ u16 f2bf(float f){
  __hip_bfloat16 h = __float2bfloat16(f);
  union { __hip_bfloat16 h; u16 u; } v; v.h = h; return v.u;
}
__device__ __forceinline__ u32 pk2bf(float lo, float hi){
  __hip_bfloat162 h = __float22bfloat162_rn(float2{lo, hi});
  union { __hip_bfloat162 h; u32 u; } v; v.h = h; return v.u;
}
__device__ __forceinline__ float bf2f(u16 h){
  union { u32 u; float f; } v; v.u = ((u32)h) << 16; return v.f;
}

// ---------------- K0: peh/v/sT, bidir(x4), WrT/brp/catx, masksumInv ----------------
__global__ void k_pre(const float* __restrict__ times, const float* __restrict__ mask,
                      const float* __restrict__ Wb, const float* __restrict__ Wrecv,
                      const float* __restrict__ brecv, const float* __restrict__ battn,
                      float* __restrict__ ws_f, char* __restrict__ ws_b) {
  __shared__ float peL[32][17];
  __shared__ float wpe[64][17];
  __shared__ float pm[4][64];
  const int blk = blockIdx.x, tid = threadIdx.x;
  u16* wrt  = (u16*)(ws_b + BOFF_WRT);
  u16* catx = (u16*)(ws_b + BOFF_CATX);
  u16* peh  = (u16*)(ws_b + BOFF_PEH);
  u16* vv   = (u16*)(ws_b + BOFF_V);
  float* ST = ws_f + OFF_ST;
  if (blk < 256) {                     // PE (bf16) + v_t + s_t for 32 bt rows
    #pragma unroll
    for (int r = 0; r < 2; ++r) {
      int id = blk * 512 + r * 256 + tid;
      int bt = id >> 4, k = id & 15;
      float tv = times[bt];
      int kk = k & 7;
      float fr = expf(-(float)kk * 1.1512925465f); // ln(1e4)/8
      float ang = tv * fr;
      float v = (k < 8) ? sinf(ang) : cosf(ang);
      peh[id] = f2bf(v);
      peL[r*16 + (tid >> 4)][k] = v;
    }
    #pragma unroll
    for (int q = 0; q < 4; ++q) {
      int idx = q * 256 + tid;
      wpe[idx >> 4][idx & 15] = Wrecv[(idx >> 4)*26 + 10 + (idx & 15)];
    }
    __syncthreads();
    {
      int btl = tid >> 3, e0 = (tid & 7) * 8;
      float acc[8];
      #pragma unroll
      for (int i = 0; i < 8; ++i) acc[i] = 0.f;
      #pragma unroll
      for (int k = 0; k < 16; ++k) {
        float p = peL[btl][k];
        #pragma unroll
        for (int i = 0; i < 8; ++i) acc[i] += wpe[e0 + i][k] * p;
      }
      u32* dst = (u32*)&vv[(blk*32 + btl)*64 + e0];
      #pragma unroll
      for (int p = 0; p < 4; ++p) dst[p] = pk2bf(acc[2*p], acc[2*p+1]);
      if (tid < 32) {
        float s = 0.f;
        #pragma unroll
        for (int k = 0; k < 16; ++k) s += brecv[10 + k] * peL[tid][k];
        ST[blk*32 + tid] = s;
      }
    }
  } else if (blk < 260) {              // bidir = Wb @ Wb^T (4 blocks)
    float* bidir = ws_f + OFF_BIDIR;
    int q = blk - 256;
    for (int rr = 0; rr < 4; ++rr) {
      int idx = (q*4 + rr) * 256 + tid;
      int i = idx >> 6, j = idx & 63;
      float acc = 0.f;
      for (int e = 0; e < 64; ++e) acc += Wb[i*64+e] * Wb[j*64+e];
      bidir[idx] = acc;
    }
  } else if (blk == 260) {             // WrT, brp (pad16), catx
    for (int r = 0; r < 8; ++r) {
      int idx = r * 256 + tid;
      int d = idx >> 6, e = idx & 63;
      wrt[idx] = (d < 26) ? f2bf(Wrecv[e*26 + d]) : (u16)0;
    }
    if (tid < 16) ws_f[OFF_BRP + tid] = (tid < 10) ? brecv[tid] : 0.f;
    #pragma unroll
    for (int i = 0; i < 4; ++i) {
      int idx = i * 256 + tid;
      int j = idx >> 4, d = idx & 15;
      catx[idx] = (d < 10) ? f2bf(battn[j*10 + d]) : ((d == 10) ? f2bf(1.f) : (u16)0);
    }
  } else {                             // masksumInv[b][i]
    int b = blk - 261;
    int i = tid & 63, q = tid >> 6;
    float s = 0.f;
    for (int t = q*32; t < q*32 + 32; ++t) s += mask[(b*128 + t)*64 + i];
    pm[q][i] = s;
    __syncthreads();
    if (tid < 64)
      (ws_f + OFF_MS)[b*64 + tid] =
          1.0f / (pm[0][tid] + pm[1][tid] + pm[2][tid] + pm[3][tid]);
  }
}

// ---------------- K1: adj2 numerator (sum_t alpha) ----------------
__global__ __launch_bounds__(256)
void k_adj(const float* __restrict__ x, const float* __restrict__ mask,
           const float* __restrict__ Wobs, float* __restrict__ ws_f,
           const char* __restrict__ ws_b) {
  __shared__ __align__(16) u16 hA[64][72];
  __shared__ __align__(16) u16 hmA[64][24];

  const int tid = threadIdx.x;
  const int b = blockIdx.y, tc = blockIdx.x;
  const int w = tid >> 6, l = tid & 63, lr = l & 15, lq = l >> 4, kb = lq * 8;
  const u16* wrt  = (const u16*)(ws_b + BOFF_WRT);
  const u16* catx = (const u16*)(ws_b + BOFF_CATX);
  const u16* vv   = (const u16*)(ws_b + BOFF_V);
  const float* brp = ws_f + OFF_BRP;
  const float* ST = ws_f + OFF_ST;
  float* adj = ws_f + OFF_ADJ;

  const short8 z8 = (short8){0,0,0,0,0,0,0,0};
  const bool lowk = (lq < 2);
  short8 w0 = z8, w1 = z8;
  if (lr < 10) {
    const u16* wr = wrt + lr * 64;
    w0 = *(const short8*)&wr[kb];
    w1 = *(const short8*)&wr[32 + kb];
  }
  short8 bc[4];
  #pragma unroll
  for (int n = 0; n < 4; ++n)
    bc[n] = lowk ? *(const short8*)&catx[(16*n + lr)*16 + lq*8] : z8;
  float4 bv = *(const float4*)&brp[lq*4];

  f32x4 asum[4];
  #pragma unroll
  for (int n = 0; n < 4; ++n) asum[n] = (f32x4){0.f,0.f,0.f,0.f};

  const int e4 = tid & 15, sg = tid >> 4;

  for (int tt = 0; tt < 8; ++tt) {
    int t = tc * 8 + tt;
    int base = b * 128 + t;
    short8 av0 = z8, av1 = z8;
    if (lr == 10) {
      av0 = *(const short8*)&vv[base*64 + kb];
      av1 = *(const short8*)&vv[base*64 + 32 + kb];
    }
    float st = ST[base];
    {
      float4 mk4 = *(const float4*)&mask[base*64 + sg*4];
      float mks[4] = {mk4.x, mk4.y, mk4.z, mk4.w};
      #pragma unroll
      for (int si = 0; si < 4; ++si) {
        int s = sg*4 + si;
        float4 xv = *(const float4*)&x[base*256 + s*4];
        float xo[4] = {xv.x, xv.y, xv.z, xv.w};
        float ax = 0.f, ay = 0.f, az = 0.f, aw = 0.f;
        #pragma unroll
        for (int o = 0; o < 4; ++o) {
          float4 wv = *(const float4*)&Wobs[(s*4+o)*64 + e4*4];
          ax += xo[o]*wv.x; ay += xo[o]*wv.y; az += xo[o]*wv.z; aw += xo[o]*wv.w;
        }
        float mk = mks[si];
        uint2 p;
        p.x = pk2bf(fmaxf(ax,0.f)*mk, fmaxf(ay,0.f)*mk);
        p.y = pk2bf(fmaxf(az,0.f)*mk, fmaxf(aw,0.f)*mk);
        *(uint2*)&hA[s][e4*4] = p;
      }
    }
    __syncthreads();
    { // P1
      short8 a0 = (lr < 10) ? w0 : av0;
      short8 a1 = (lr < 10) ? w1 : av1;
      f32x4 acc = (f32x4){0.f,0.f,0.f,0.f};
      short8 b0 = *(const short8*)&hA[16*w + lr][kb];
      short8 b1 = *(const short8*)&hA[16*w + lr][32 + kb];
      acc = __builtin_amdgcn_mfma_f32_16x16x32_bf16(a0, b0, acc, 0, 0, 0);
      acc = __builtin_amdgcn_mfma_f32_16x16x32_bf16(a1, b1, acc, 0, 0, 0);
      uint2 qq;
      qq.x = pk2bf(acc[0]+bv.x, acc[1]+bv.y);
      qq.y = pk2bf(acc[2]+bv.z, acc[3]+bv.w);
      *(uint2*)&hmA[16*w + lr][lq*4] = qq;
    }
    __syncthreads();
    { // P2
      short8 am = lowk ? *(const short8*)&hmA[16*w + lr][lq*8] : z8;
      #pragma unroll
      for (int n = 0; n < 4; ++n) {
        f32x4 z = (f32x4){st, st, st, st};
        z = __builtin_amdgcn_mfma_f32_16x16x32_bf16(am, bc[n], z, 0, 0, 0);
        #pragma unroll
        for (int reg = 0; reg < 4; ++reg) asum[n][reg] += fmaxf(z[reg], 0.f);
      }
    }
    __syncthreads();
  }
  #pragma unroll
  for (int n = 0; n < 4; ++n) {
    #pragma unroll
    for (int reg = 0; reg < 4; ++reg) {
      int i = 16*w + lq*4 + reg, j = 16*n + lr;
      atomicAdd(&adj[((size_t)b << 12) + (i << 6) + j], asum[n][reg]);
    }
  }
}

// ---------------- K1b: adjS = bf16(adjnum * msInv) ----------------
__global__ __launch_bounds__(256)
void k_scale(const float* __restrict__ ws_f, char* __restrict__ ws_b) {
  const int b = blockIdx.x, tid = threadIdx.x;
  const float* adj = ws_f + OFF_ADJ + (size_t)b * 4096;
  const float* msI = ws_f + OFF_MS + b * 64;
  u16* as_ = (u16*)(ws_b + BOFF_ADJS) + (size_t)b * 4096;
  #pragma unroll
  for (int k = 0; k < 16; ++k) {
    int idx = k * 256 + tid;
    int i = idx >> 6;
    as_[idx] = f2bf(adj[idx] * msI[i]);
  }
}

// ---------------- K2: full per-(b,t) chain -> Hh bf16 (1 t/block) ----------------
__global__ __launch_bounds__(256, 4)
void k_main(const float* __restrict__ x, const float* __restrict__ mask,
            const float* __restrict__ Wobs, const float* __restrict__ ws_f,
            const char* __restrict__ ws_b, u16* __restrict__ Hh) {
  __shared__ __align__(16) char smem[36864];
  u16 (*hA)[72]  = (u16 (*)[72])(smem);           // h [s][e]; later h1T [e][i]
  u16 (*hT)[72]  = (u16 (*)[72])(smem + 9216);    // h^T [e][s]
  u16 (*wA)[72]  = (u16 (*)[72])(smem + 18432);   // w1 [i][j]
  u16 (*hmA)[24] = (u16 (*)[24])(smem + 27648);   // hmx [s][dx]  (dead after P2)
  u16 (*adjS)[72]= (u16 (*)[72])(smem + 27648);   // overlay, staged in P3

  const int tid = threadIdx.x;
  const int t = blockIdx.x, b = blockIdx.y;
  const int w = tid >> 6, l = tid & 63, lr = l & 15, lq = l >> 4, kb = lq * 8;
  const int base = b * 128 + t;
  const u16* wrt  = (const u16*)(ws_b + BOFF_WRT);
  const u16* catx = (const u16*)(ws_b + BOFF_CATX);
  const u16* vv   = (const u16*)(ws_b + BOFF_V);
  const float* bidirG = ws_f + OFF_BIDIR;
  const float* brp = ws_f + OFF_BRP;
  const int i0 = 16*w + lq*4;
  const short8 z8 = (short8){0,0,0,0,0,0,0,0};
  const bool lowk = (lq < 2);

  // ---- prefetches: long-latency loads issued before any compute ----
  const uint4* ag = (const uint4*)(ws_b + BOFF_ADJS + (size_t)b * 8192);
  uint4 g0 = ag[2*tid], g1 = ag[2*tid + 1];
  short8 w0 = z8, w1 = z8;
  if (lr < 10) {
    const u16* wr = wrt + lr * 64;
    w0 = *(const short8*)&wr[kb];
    w1 = *(const short8*)&wr[32 + kb];
  }
  short8 av0 = z8, av1 = z8;
  if (lr == 10) {
    av0 = *(const short8*)&vv[base*64 + kb];
    av1 = *(const short8*)&vv[base*64 + 32 + kb];
  }
  short8 bc[4];
  #pragma unroll
  for (int n = 0; n < 4; ++n)
    bc[n] = lowk ? *(const short8*)&catx[(16*n + lr)*16 + lq*8] : z8;
  float4 bv = *(const float4*)&brp[lq*4];
  const float st = (ws_f + OFF_ST)[base];

  { // P0: h build (direct x/mask loads)
    const int e4 = tid & 15, sg = tid >> 4;
    float4 mk4 = *(const float4*)&mask[base*64 + sg*4];
    float mks[4] = {mk4.x, mk4.y, mk4.z, mk4.w};
    #pragma unroll
    for (int si = 0; si < 4; ++si) {
      int s = sg*4 + si;
      float4 xv = *(const float4*)&x[base*256 + s*4];
      float xo[4] = {xv.x, xv.y, xv.z, xv.w};
      float ax = 0.f, ay = 0.f, az = 0.f, aw = 0.f;
      #pragma unroll
      for (int o = 0; o < 4; ++o) {
        float4 wv = *(const float4*)&Wobs[(s*4+o)*64 + e4*4];
        ax += xo[o]*wv.x; ay += xo[o]*wv.y; az += xo[o]*wv.z; aw += xo[o]*wv.w;
      }
      float mk = mks[si];
      uint2 p;
      p.x = pk2bf(fmaxf(ax,0.f)*mk, fmaxf(ay,0.f)*mk);
      p.y = pk2bf(fmaxf(az,0.f)*mk, fmaxf(aw,0.f)*mk);
      *(uint2*)&hA[s][e4*4] = p;
    }
  }
  __syncthreads();

  { // P1: hT rebuild + hmx MFMA
    #pragma unroll
    for (int sp = 0; sp < 8; ++sp) {
      int s = w*16 + sp*2;
      *(u32*)&hT[l][s] = (u32)hA[s][l] | ((u32)hA[s+1][l] << 16);
    }
    short8 a0 = (lr < 10) ? w0 : av0;
    short8 a1 = (lr < 10) ? w1 : av1;
    f32x4 acc = (f32x4){0.f,0.f,0.f,0.f};
    short8 b0 = *(const short8*)&hA[16*w + lr][kb];
    short8 b1 = *(const short8*)&hA[16*w + lr][32 + kb];
    acc = __builtin_amdgcn_mfma_f32_16x16x32_bf16(a0, b0, acc, 0, 0, 0);
    acc = __builtin_amdgcn_mfma_f32_16x16x32_bf16(a1, b1, acc, 0, 0, 0);
    uint2 qq;
    qq.x = pk2bf(acc[0]+bv.x, acc[1]+bv.y);
    qq.y = pk2bf(acc[2]+bv.z, acc[3]+bv.w);
    *(uint2*)&hmA[16*w + lr][lq*4] = qq;
  }
  __syncthreads();

  { // P2: alpha -> w1 (wA)
    short8 am = lowk ? *(const short8*)&hmA[16*w + lr][lq*8] : z8;
    #pragma unroll
    for (int n = 0; n < 4; ++n) {
      f32x4 z = (f32x4){st, st, st, st};
      z = __builtin_amdgcn_mfma_f32_16x16x32_bf16(am, bc[n], z, 0, 0, 0);
      int j = 16*n + lr;
      #pragma unroll
      for (int reg = 0; reg < 4; ++reg) {
        float w1v = fmaxf(z[reg], 0.f) * bidirG[((i0+reg) << 6) + j];
        wA[i0 + reg][j] = f2bf(w1v);
      }
    }
  }
  __syncthreads();

  { // P3: adjS regs -> LDS (overlay); h1 = relu(w1 @ h) -> h1T into hA
    int idx0 = 2*tid, idx1 = 2*tid + 1;
    *(uint4*)&adjS[idx0 >> 3][(idx0 & 7) * 8] = g0;
    *(uint4*)&adjS[idx1 >> 3][(idx1 & 7) * 8] = g1;

    short8 aw0 = *(const short8*)&wA[16*w + lr][kb];
    short8 aw1 = *(const short8*)&wA[16*w + lr][32 + kb];
    #pragma unroll
    for (int n = 0; n < 4; ++n) {
      f32x4 acc = (f32x4){0.f,0.f,0.f,0.f};
      short8 b0 = *(const short8*)&hT[16*n + lr][kb];
      short8 b1 = *(const short8*)&hT[16*n + lr][32 + kb];
      acc = __builtin_amdgcn_mfma_f32_16x16x32_bf16(aw0, b0, acc, 0, 0, 0);
      acc = __builtin_amdgcn_mfma_f32_16x16x32_bf16(aw1, b1, acc, 0, 0, 0);
      int e = 16*n + lr;
      uint2 pp;
      pp.x = pk2bf(fmaxf(acc[0],0.f), fmaxf(acc[1],0.f));
      pp.y = pk2bf(fmaxf(acc[2],0.f), fmaxf(acc[3],0.f));
      *(uint2*)&hA[e][i0] = pp;   // h1T[e][i]
    }
  }
  __syncthreads();

  { // P4: w2 = w1 (.) adjS; h2 = relu(w2 @ h1) -> Hh
    int row = 16*w + lr;
    union { short8 v; u16 h[8]; u32 u[4]; } uw0, uw1, ud0, ud1, oa, ob;
    uw0.v = *(const short8*)&wA[row][kb];
    uw1.v = *(const short8*)&wA[row][32 + kb];
    ud0.v = *(const short8*)&adjS[row][kb];
    ud1.v = *(const short8*)&adjS[row][32 + kb];
    #pragma unroll
    for (int k = 0; k < 4; ++k) {
      oa.u[k] = pk2bf(bf2f(uw0.h[2*k])*bf2f(ud0.h[2*k]),
                      bf2f(uw0.h[2*k+1])*bf2f(ud0.h[2*k+1]));
      ob.u[k] = pk2bf(bf2f(uw1.h[2*k])*bf2f(ud1.h[2*k]),
                      bf2f(uw1.h[2*k+1])*bf2f(ud1.h[2*k+1]));
    }
    short8 a20 = oa.v, a21 = ob.v;
    size_t obase = ((size_t)b * 64) * 8192 + (size_t)t * 64;
    #pragma unroll
    for (int n = 0; n < 4; ++n) {
      f32x4 acc = (f32x4){0.f,0.f,0.f,0.f};
      short8 b0 = *(const short8*)&hA[16*n + lr][kb];      // h1T
      short8 b1 = *(const short8*)&hA[16*n + lr][32 + kb];
      acc = __builtin_amdgcn_mfma_f32_16x16x32_bf16(a20, b0, acc, 0, 0, 0);
      acc = __builtin_amdgcn_mfma_f32_16x16x32_bf16(a21, b1, acc, 0, 0, 0);
      int e = 16*n + lr;
      u32 p0 = pk2bf(fmaxf(acc[0],0.f), fmaxf(acc[1],0.f));
      u32 p1 = pk2bf(fmaxf(acc[2],0.f), fmaxf(acc[3],0.f));
      Hh[obase + (size_t)(i0+0) * 8192 + e] = (u16)p0;
      Hh[obase + (size_t)(i0+1) * 8192 + e] = (u16)(p0 >> 16);
      Hh[obase + (size_t)(i0+2) * 8192 + e] = (u16)p1;
      Hh[obase + (size_t)(i0+3) * 8192 + e] = (u16)(p1 >> 16);
    }
  }
}

// ---------------- K3: collapsed temporal attention (512 threads, bf16 PE) ----------------
#define HTP 82

__global__ __launch_bounds__(512)
void k_attn(const char* __restrict__ ws_b, const u16* __restrict__ Hh,
            const float* __restrict__ Wq, const float* __restrict__ bq,
            const float* __restrict__ Wk, const float* __restrict__ bk,
            const float* __restrict__ Ws, const float* __restrict__ bs,
            const float* __restrict__ Wemb, const float* __restrict__ bemb,
            float* __restrict__ out) {
  __shared__ u16 Ht[128][HTP];
  __shared__ u16 peB[128][18];
  __shared__ float wsL[128];
  __shared__ float pA[6][80];
  __shared__ float pK[8][10];
  __shared__ float qvL[80];
  __shared__ float pC[4][128];
  __shared__ float bb[128];
  __shared__ float red[4];
  __shared__ float cstL, sWL;

  const int tid = threadIdx.x;
  const int s = blockIdx.x, b = blockIdx.y;
  const float scale = 0.111803398875f; // 1/sqrt(80)
  const u16* peh = (const u16*)(ws_b + BOFF_PEH);

  const u16* src = Hh + ((size_t)b * 64 + s) * 8192;
  #pragma unroll
  for (int r = 0; r < 2; ++r) {
    int id = r * 512 + tid;
    int tt = id >> 3, c = (id & 7) * 8;
    uint4 q = *(const uint4*)&src[tt * 64 + c];
    u32* dst = (u32*)&Ht[tt][c];
    dst[0] = q.x; dst[1] = q.y; dst[2] = q.z; dst[3] = q.w;
  }
  #pragma unroll
  for (int r = 0; r < 2; ++r) {
    int id = r * 512 + tid;              // 1024 u32 = 2048 u16 PE values
    u32 pv = ((const u32*)(peh + (size_t)b * 2048))[id];
    *(u32*)&peB[id >> 3][(id & 7) * 2] = pv;
  }
  if (tid < 128) wsL[tid] = Ws[tid];
  __syncthreads();

  // Phase A: hbar partials over 6 t-chunks of ~22
  if (tid < 480) {
    int d = tid % 80, c = tid / 80;
    int t0 = c * 22, t1 = (t0 + 22 > 128) ? 128 : t0 + 22;
    float a0 = 0.f, a1 = 0.f, a2 = 0.f, a3 = 0.f;
    int t = t0;
    if (d < 64) {
      for (; t + 4 <= t1; t += 4) {
        a0 += wsL[t]   * bf2f(Ht[t][d]);
        a1 += wsL[t+1] * bf2f(Ht[t+1][d]);
        a2 += wsL[t+2] * bf2f(Ht[t+2][d]);
        a3 += wsL[t+3] * bf2f(Ht[t+3][d]);
      }
      for (; t < t1; ++t) a0 += wsL[t] * bf2f(Ht[t][d]);
    } else {
      int k = d - 64;
      for (; t + 4 <= t1; t += 4) {
        a0 += wsL[t]   * bf2f(peB[t][k]);
        a1 += wsL[t+1] * bf2f(peB[t+1][k]);
        a2 += wsL[t+2] * bf2f(peB[t+2][k]);
        a3 += wsL[t+3] * bf2f(peB[t+3][k]);
      }
      for (; t < t1; ++t) a0 += wsL[t] * bf2f(peB[t][k]);
    }
    pA[c][d] = (a0 + a1) + (a2 + a3);
  } else if (tid == 480) {
    float a0 = 0.f, a1 = 0.f, a2 = 0.f, a3 = 0.f;
    for (int t = 0; t < 128; t += 4) {
      a0 += wsL[t]; a1 += wsL[t+1]; a2 += wsL[t+2]; a3 += wsL[t+3];
    }
    sWL = (a0 + a1) + (a2 + a3);
  }
  __syncthreads();

  if (tid < 80) {
    int a = tid % 10, c = tid / 10;
    float a0 = 0.f, a1 = 0.f;
    #pragma unroll
    for (int i = 0; i < 10; i += 2) {
      int d = c * 10 + i;
      float h0 = pA[0][d] + pA[1][d] + pA[2][d] + pA[3][d] + pA[4][d] + pA[5][d];
      float h1 = pA[0][d+1] + pA[1][d+1] + pA[2][d+1] + pA[3][d+1] + pA[4][d+1] + pA[5][d+1];
      a0 += h0 * Wk[d * 10 + a];
      a1 += h1 * Wk[(d+1) * 10 + a];
    }
    pK[c][a] = a0 + a1;
  }
  __syncthreads();

  if (tid <= 80) {
    float kt[10];
    #pragma unroll
    for (int a = 0; a < 10; ++a) {
      float acc = sWL * bk[a];
      #pragma unroll
      for (int c = 0; c < 8; ++c) acc += pK[c][a];
      kt[a] = acc;
    }
    if (tid < 80) {
      float a0 = 0.f, a1 = 0.f;
      #pragma unroll
      for (int a = 0; a < 10; a += 2) {
        a0 += Wq[tid * 10 + a] * kt[a];
        a1 += Wq[tid * 10 + a + 1] * kt[a + 1];
      }
      qvL[tid] = a0 + a1;
    } else {
      float cq = 0.f;
      #pragma unroll
      for (int a = 0; a < 10; ++a) cq += bq[a] * kt[a];
      cstL = scale * cq + bs[0];
    }
  }
  __syncthreads();

  // Phase C: beta partials over 4 d-quarters
  {
    int t = tid & 127, q = tid >> 7;
    float a0 = 0.f, a1 = 0.f, a2 = 0.f, a3 = 0.f;
    const u32* row = (const u32*)&Ht[t][0];
    if (q == 0) {
      #pragma unroll
      for (int i = 0; i < 10; i += 2) {
        u32 p0 = row[i], p1 = row[i+1];
        a0 += bf2f((u16)p0) * qvL[2*i]   + bf2f((u16)(p0 >> 16)) * qvL[2*i+1];
        a1 += bf2f((u16)p1) * qvL[2*i+2] + bf2f((u16)(p1 >> 16)) * qvL[2*i+3];
      }
    } else if (q == 1) {
      #pragma unroll
      for (int i = 10; i < 20; i += 2) {
        u32 p0 = row[i], p1 = row[i+1];
        a0 += bf2f((u16)p0) * qvL[2*i]   + bf2f((u16)(p0 >> 16)) * qvL[2*i+1];
        a1 += bf2f((u16)p1) * qvL[2*i+2] + bf2f((u16)(p1 >> 16)) * qvL[2*i+3];
      }
    } else if (q == 2) {
      #pragma unroll
      for (int i = 20; i < 32; i += 4) {
        u32 p0 = row[i], p1 = row[i+1], p2 = row[i+2], p3 = row[i+3];
        a0 += bf2f((u16)p0) * qvL[2*i]   + bf2f((u16)(p0 >> 16)) * qvL[2*i+1];
        a1 += bf2f((u16)p1) * qvL[2*i+2] + bf2f((u16)(p1 >> 16)) * qvL[2*i+3];
        a2 += bf2f((u16)p2) * qvL[2*i+4] + bf2f((u16)(p2 >> 16)) * qvL[2*i+5];
        a3 += bf2f((u16)p3) * qvL[2*i+6] + bf2f((u16)(p3 >> 16)) * qvL[2*i+7];
      }
    } else {
      #pragma unroll
      for (int k = 0; k < 16; k += 4) {
        a0 += bf2f(peB[t][k])   * qvL[64 + k];
        a1 += bf2f(peB[t][k+1]) * qvL[65 + k];
        a2 += bf2f(peB[t][k+2]) * qvL[66 + k];
        a3 += bf2f(peB[t][k+3]) * qvL[67 + k];
      }
    }
    pC[q][t] = (a0 + a1) + (a2 + a3);
  }
  __syncthreads();

  if (tid < 128) {
    float v = scale * (pC[0][tid] + pC[1][tid] + pC[2][tid] + pC[3][tid]) + cstL;
    bb[tid] = v;
    float mm = v;
    #pragma unroll
    for (int off = 32; off; off >>= 1) mm = fmaxf(mm, __shfl_xor(mm, off));
    if ((tid & 63) == 0) red[tid >> 6] = mm;
  }
  __syncthreads();
  float mx = fmaxf(red[0], red[1]);
  if (tid < 128) {
    float ev = expf(bb[tid] - mx);
    bb[tid] = ev;
    float ss = ev;
    #pragma unroll
    for (int off = 32; off; off >>= 1) ss += __shfl_xor(ss, off);
    if ((tid & 63) == 0) red[2 + (tid >> 6)] = ss;
  }
  __syncthreads();

  // Phase E: hout partials (reuse pA), 6 t-chunks
  if (tid < 480) {
    int d = tid % 80, c = tid / 80;
    int t0 = c * 22, t1 = (t0 + 22 > 128) ? 128 : t0 + 22;
    float a0 = 0.f, a1 = 0.f, a2 = 0.f, a3 = 0.f;
    int t = t0;
    if (d < 64) {
      for (; t + 4 <= t1; t += 4) {
        a0 += bb[t]   * bf2f(Ht[t][d]);
        a1 += bb[t+1] * bf2f(Ht[t+1][d]);
        a2 += bb[t+2] * bf2f(Ht[t+2][d]);
        a3 += bb[t+3] * bf2f(Ht[t+3][d]);
      }
      for (; t < t1; ++t) a0 += bb[t] * bf2f(Ht[t][d]);
    } else {
      int k = d - 64;
      for (; t + 4 <= t1; t += 4) {
        a0 += bb[t]   * bf2f(peB[t][k]);
        a1 += bb[t+1] * bf2f(peB[t+1][k]);
        a2 += bb[t+2] * bf2f(peB[t+2][k]);
        a3 += bb[t+3] * bf2f(peB[t+3][k]);
      }
      for (; t < t1; ++t) a0 += bb[t] * bf2f(peB[t][k]);
    }
    pA[c][d] = (a0 + a1) + (a2 + a3);
  }
  __syncthreads();

  // Phase F: out partials over 4 d-chunks of 20 (reuse pC)
  {
    int o = tid & 127, q = tid >> 7;
    int d0 = q * 20;
    float a0 = 0.f, a1 = 0.f, a2 = 0.f, a3 = 0.f;
    #pragma unroll
    for (int i = 0; i < 20; i += 4) {
      int d = d0 + i;
      float h0 = pA[0][d]   + pA[1][d]   + pA[2][d]   + pA[3][d]   + pA[4][d]   + pA[5][d];
      float h1 = pA[0][d+1] + pA[1][d+1] + pA[2][d+1] + pA[3][d+1] + pA[4][d+1] + pA[5][d+1];
      float h2 = pA[0][d+2] + pA[1][d+2] + pA[2][d+2] + pA[3][d+2] + pA[4][d+2] + pA[5][d+2];
      float h3 = pA[0][d+3] + pA[1][d+3] + pA[2][d+3] + pA[3][d+3] + pA[4][d+3] + pA[5][d+3];
      a0 += h0 * Wemb[d * 128 + o];
      a1 += h1 * Wemb[(d+1) * 128 + o];
      a2 += h2 * Wemb[(d+2) * 128 + o];
      a3 += h3 * Wemb[(d+3) * 128 + o];
    }
    pC[q][o] = (a0 + a1) + (a2 + a3);
  }
  __syncthreads();
  if (tid < 128) {
    float rdenom = 1.0f / (red[2] + red[3]);
    out[(((size_t)b * 64 + s) << 7) + tid] =
        bemb[tid] + (pC[0][tid] + pC[1][tid] + pC[2][tid] + pC[3][tid]) * rdenom;
  }
}

extern "C" void kernel_launch(void* const* d_in, const int* in_sizes, int n_in,
                              void* d_out, int out_size, void* d_ws, size_t ws_size,
                              hipStream_t stream) {
  (void)in_sizes; (void)n_in; (void)out_size; (void)ws_size;
  const float* x     = (const float*)d_in[0];
  const float* times = (const float*)d_in[1];
  const float* mask  = (const float*)d_in[2];
  const float* Wobs  = (const float*)d_in[3];
  const float* Wattn = (const float*)d_in[4];
  const float* Wrecv = (const float*)d_in[5];
  const float* brecv = (const float*)d_in[6];
  const float* Wb    = (const float*)d_in[7];
  const float* Wq    = (const float*)d_in[8];
  const float* bq    = (const float*)d_in[9];
  const float* Wk    = (const float*)d_in[10];
  const float* bk    = (const float*)d_in[11];
  const float* Ws    = (const float*)d_in[12];
  const float* bs    = (const float*)d_in[13];
  const float* Wemb  = (const float*)d_in[14];
  const float* bemb  = (const float*)d_in[15];
  float* out = (float*)d_out;
  float* ws_f = (float*)d_ws;
  char* ws_b = (char*)d_ws;
  u16* Hh = (u16*)(ws_b + BOFF_HH);

  hipMemsetAsync(ws_b + (size_t)OFF_ADJ * 4, 0, (size_t)64 * 64 * 64 * 4, stream);
  k_pre<<<325, 256, 0, stream>>>(times, mask, Wb, Wrecv, brecv, Wattn, ws_f, ws_b);
  k_adj<<<dim3(16, 64), 256, 0, stream>>>(x, mask, Wobs, ws_f, ws_b);
  k_scale<<<64, 256, 0, stream>>>(ws_f, ws_b);
  k_main<<<dim3(128, 64), 256, 0, stream>>>(x, mask, Wobs, ws_f, ws_b, Hh);
  k_attn<<<dim3(64, 64), 512, 0, stream>>>(ws_b, Hh, Wq, bq, Wk, bk, Ws, bs, Wemb, bemb, out);
}

// Round 12
// 137.007 us; speedup vs baseline: 1.1776x; 1.0943x over previous
//
#include <hip/hip_runtime.h>
#include <hip/hip_bf16.h>

// Raindrop forward, MI355X. B=64 T=128 S=64 O=4 E=64 P=16 A=10 OUT=128.
//  - temporal attention collapsed: (Q K^T) W_s = Q (W_s^T K)  -> no TxT matrix
//  - alpha decomposition: alpha[i][j] = relu(hm10[i]*battn[j] + h[i].v_t + s_t)
//  - NEW: k_adj persists hTg (h^T bf16) + W1p (w1 lane-packed bf16);
//    k_main is now just prop1+prop2 (2 barriers, no h/alpha recompute)
//  - memset folded into k_pre (zero blocks)
// ws floats: bidir | masksumInv | adjnum | brp[16] | sT[8192]
// ws bytes @: WrT 1638464 | catx 1642560 | PEh 1644608 | adjS 1906752 | V 2431040 |
//             W1p 3479616 | hTg 70588480 | Hh 137697344  (~196 MB total)

typedef unsigned short u16;
typedef unsigned int u32;
typedef __attribute__((ext_vector_type(8))) short short8;
typedef __attribute__((ext_vector_type(4))) float f32x4;

#define OFF_BIDIR 131072
#define OFF_MS    135168
#define OFF_ADJ   139264
#define OFF_BRP   401408
#define OFF_ST    401424
#define BOFF_WRT  1638464u
#define BOFF_CATX 1642560u
#define BOFF_PEH  1644608u
#define BOFF_ADJS 1906752u
#define BOFF_V    2431040u
#define BOFF_W1   3479616u
#define BOFF_HT   70588480u
#define BOFF_HH   137697344u

__device__ __forceinline__ u16 f2bf(float f){
  __hip_bfloat16 h = __float2bfloat16(f);
  union { __hip_bfloat16 h; u16 u; } v; v.h = h; return v.u;
}
__device__ __forceinline__ u32 pk2bf(float lo, float hi){
  __hip_bfloat162 h = __float22bfloat162_rn(float2{lo, hi});
  union { __hip_bfloat162 h; u32 u; } v; v.h = h; return v.u;
}
__device__ __forceinline__ float bf2f(u16 h){
  union { u32 u; float f; } v; v.u = ((u32)h) << 16; return v.f;
}

// ---------------- K0: peh/v/sT, bidir, WrT/brp/catx, masksumInv, adjnum zero ----------------
__global__ void k_pre(const float* __restrict__ times, const float* __restrict__ mask,
                      const float* __restrict__ Wb, const float* __restrict__ Wrecv,
                      const float* __restrict__ brecv, const float* __restrict__ battn,
                      float* __restrict__ ws_f, char* __restrict__ ws_b) {
  __shared__ float peL[32][17];
  __shared__ float wpe[64][17];
  __shared__ float pm[4][64];
  const int blk = blockIdx.x, tid = threadIdx.x;
  u16* wrt  = (u16*)(ws_b + BOFF_WRT);
  u16* catx = (u16*)(ws_b + BOFF_CATX);
  u16* peh  = (u16*)(ws_b + BOFF_PEH);
  u16* vv   = (u16*)(ws_b + BOFF_V);
  float* ST = ws_f + OFF_ST;
  if (blk < 256) {                     // PE (bf16) + v_t + s_t for 32 bt rows
    #pragma unroll
    for (int r = 0; r < 2; ++r) {
      int id = blk * 512 + r * 256 + tid;
      int bt = id >> 4, k = id & 15;
      float tv = times[bt];
      int kk = k & 7;
      float fr = expf(-(float)kk * 1.1512925465f); // ln(1e4)/8
      float ang = tv * fr;
      float v = (k < 8) ? sinf(ang) : cosf(ang);
      peh[id] = f2bf(v);
      peL[r*16 + (tid >> 4)][k] = v;
    }
    #pragma unroll
    for (int q = 0; q < 4; ++q) {
      int idx = q * 256 + tid;
      wpe[idx >> 4][idx & 15] = Wrecv[(idx >> 4)*26 + 10 + (idx & 15)];
    }
    __syncthreads();
    {
      int btl = tid >> 3, e0 = (tid & 7) * 8;
      float acc[8];
      #pragma unroll
      for (int i = 0; i < 8; ++i) acc[i] = 0.f;
      #pragma unroll
      for (int k = 0; k < 16; ++k) {
        float p = peL[btl][k];
        #pragma unroll
        for (int i = 0; i < 8; ++i) acc[i] += wpe[e0 + i][k] * p;
      }
      u32* dst = (u32*)&vv[(blk*32 + btl)*64 + e0];
      #pragma unroll
      for (int p = 0; p < 4; ++p) dst[p] = pk2bf(acc[2*p], acc[2*p+1]);
      if (tid < 32) {
        float s = 0.f;
        #pragma unroll
        for (int k = 0; k < 16; ++k) s += brecv[10 + k] * peL[tid][k];
        ST[blk*32 + tid] = s;
      }
    }
  } else if (blk < 260) {              // bidir = Wb @ Wb^T (4 blocks)
    float* bidir = ws_f + OFF_BIDIR;
    int q = blk - 256;
    for (int rr = 0; rr < 4; ++rr) {
      int idx = (q*4 + rr) * 256 + tid;
      int i = idx >> 6, j = idx & 63;
      float acc = 0.f;
      for (int e = 0; e < 64; ++e) acc += Wb[i*64+e] * Wb[j*64+e];
      bidir[idx] = acc;
    }
  } else if (blk == 260) {             // WrT, brp (pad16), catx
    for (int r = 0; r < 8; ++r) {
      int idx = r * 256 + tid;
      int d = idx >> 6, e = idx & 63;
      wrt[idx] = (d < 26) ? f2bf(Wrecv[e*26 + d]) : (u16)0;
    }
    if (tid < 16) ws_f[OFF_BRP + tid] = (tid < 10) ? brecv[tid] : 0.f;
    #pragma unroll
    for (int i = 0; i < 4; ++i) {
      int idx = i * 256 + tid;
      int j = idx >> 4, d = idx & 15;
      catx[idx] = (d < 10) ? f2bf(battn[j*10 + d]) : ((d == 10) ? f2bf(1.f) : (u16)0);
    }
  } else if (blk < 325) {              // masksumInv[b][i]
    int b = blk - 261;
    int i = tid & 63, q = tid >> 6;
    float s = 0.f;
    for (int t = q*32; t < q*32 + 32; ++t) s += mask[(b*128 + t)*64 + i];
    pm[q][i] = s;
    __syncthreads();
    if (tid < 64)
      (ws_f + OFF_MS)[b*64 + tid] =
          1.0f / (pm[0][tid] + pm[1][tid] + pm[2][tid] + pm[3][tid]);
  } else {                             // zero adjnum (16 blocks x 64 KB)
    int zb = blk - 325;
    float4 z4 = {0.f, 0.f, 0.f, 0.f};
    float4* dst = (float4*)(ws_f + OFF_ADJ);
    #pragma unroll
    for (int r = 0; r < 16; ++r) dst[zb*4096 + r*256 + tid] = z4;
  }
}

// ---------------- K1: adj2 numerator + persist hTg, W1p ----------------
__global__ __launch_bounds__(256)
void k_adj(const float* __restrict__ x, const float* __restrict__ mask,
           const float* __restrict__ Wobs, float* __restrict__ ws_f,
           char* __restrict__ ws_b) {
  __shared__ __align__(16) u16 hA[64][72];
  __shared__ __align__(16) u16 hmA[64][24];

  const int tid = threadIdx.x;
  const int b = blockIdx.y, tc = blockIdx.x;
  const int w = tid >> 6, l = tid & 63, lr = l & 15, lq = l >> 4, kb = lq * 8;
  const int i0 = 16*w + lq*4;
  const u16* wrt  = (const u16*)(ws_b + BOFF_WRT);
  const u16* catx = (const u16*)(ws_b + BOFF_CATX);
  const u16* vv   = (const u16*)(ws_b + BOFF_V);
  const float* brp = ws_f + OFF_BRP;
  const float* ST = ws_f + OFF_ST;
  const float* bidirG = ws_f + OFF_BIDIR;
  float* adj = ws_f + OFF_ADJ;

  const short8 z8 = (short8){0,0,0,0,0,0,0,0};
  const bool lowk = (lq < 2);
  short8 w0 = z8, w1 = z8;
  if (lr < 10) {
    const u16* wr = wrt + lr * 64;
    w0 = *(const short8*)&wr[kb];
    w1 = *(const short8*)&wr[32 + kb];
  }
  short8 bc[4];
  #pragma unroll
  for (int n = 0; n < 4; ++n)
    bc[n] = lowk ? *(const short8*)&catx[(16*n + lr)*16 + lq*8] : z8;
  float4 bv = *(const float4*)&brp[lq*4];
  float bidirR[4][4];
  #pragma unroll
  for (int n = 0; n < 4; ++n)
    #pragma unroll
    for (int reg = 0; reg < 4; ++reg)
      bidirR[n][reg] = bidirG[((i0+reg) << 6) + 16*n + lr];

  f32x4 asum[4];
  #pragma unroll
  for (int n = 0; n < 4; ++n) asum[n] = (f32x4){0.f,0.f,0.f,0.f};

  const int e4 = tid & 15, sg = tid >> 4;

  for (int tt = 0; tt < 8; ++tt) {
    int t = tc * 8 + tt;
    int base = b * 128 + t;
    short8 av0 = z8, av1 = z8;
    if (lr == 10) {
      av0 = *(const short8*)&vv[base*64 + kb];
      av1 = *(const short8*)&vv[base*64 + 32 + kb];
    }
    float st = ST[base];
    { // P0: h build; write hA + transposed global hTg
      float4 mk4 = *(const float4*)&mask[base*64 + sg*4];
      float mks[4] = {mk4.x, mk4.y, mk4.z, mk4.w};
      u16 hv[4][4];
      #pragma unroll
      for (int si = 0; si < 4; ++si) {
        int s = sg*4 + si;
        float4 xv = *(const float4*)&x[base*256 + s*4];
        float xo[4] = {xv.x, xv.y, xv.z, xv.w};
        float ax = 0.f, ay = 0.f, az = 0.f, aw = 0.f;
        #pragma unroll
        for (int o = 0; o < 4; ++o) {
          float4 wv = *(const float4*)&Wobs[(s*4+o)*64 + e4*4];
          ax += xo[o]*wv.x; ay += xo[o]*wv.y; az += xo[o]*wv.z; aw += xo[o]*wv.w;
        }
        float mk = mks[si];
        uint2 p;
        p.x = pk2bf(fmaxf(ax,0.f)*mk, fmaxf(ay,0.f)*mk);
        p.y = pk2bf(fmaxf(az,0.f)*mk, fmaxf(aw,0.f)*mk);
        *(uint2*)&hA[s][e4*4] = p;
        hv[si][0] = (u16)p.x; hv[si][1] = (u16)(p.x >> 16);
        hv[si][2] = (u16)p.y; hv[si][3] = (u16)(p.y >> 16);
      }
      u16* hTg = (u16*)(ws_b + BOFF_HT) + (size_t)base * 4096;
      #pragma unroll
      for (int k = 0; k < 4; ++k) {
        uint2 q;
        q.x = (u32)hv[0][k] | ((u32)hv[1][k] << 16);
        q.y = (u32)hv[2][k] | ((u32)hv[3][k] << 16);
        *(uint2*)&hTg[(e4*4 + k)*64 + sg*4] = q;
      }
    }
    __syncthreads();
    { // P1: hmx
      short8 a0 = (lr < 10) ? w0 : av0;
      short8 a1 = (lr < 10) ? w1 : av1;
      f32x4 acc = (f32x4){0.f,0.f,0.f,0.f};
      short8 b0 = *(const short8*)&hA[16*w + lr][kb];
      short8 b1 = *(const short8*)&hA[16*w + lr][32 + kb];
      acc = __builtin_amdgcn_mfma_f32_16x16x32_bf16(a0, b0, acc, 0, 0, 0);
      acc = __builtin_amdgcn_mfma_f32_16x16x32_bf16(a1, b1, acc, 0, 0, 0);
      uint2 qq;
      qq.x = pk2bf(acc[0]+bv.x, acc[1]+bv.y);
      qq.y = pk2bf(acc[2]+bv.z, acc[3]+bv.w);
      *(uint2*)&hmA[16*w + lr][lq*4] = qq;
    }
    __syncthreads();
    { // P2: alpha; accumulate asum; write lane-packed w1
      short8 am = lowk ? *(const short8*)&hmA[16*w + lr][lq*8] : z8;
      u32 w1u[8];
      #pragma unroll
      for (int n = 0; n < 4; ++n) {
        f32x4 z = (f32x4){st, st, st, st};
        z = __builtin_amdgcn_mfma_f32_16x16x32_bf16(am, bc[n], z, 0, 0, 0);
        float w1v[4];
        #pragma unroll
        for (int reg = 0; reg < 4; ++reg) {
          float al = fmaxf(z[reg], 0.f);
          asum[n][reg] += al;
          w1v[reg] = al * bidirR[n][reg];
        }
        w1u[2*n]   = pk2bf(w1v[0], w1v[1]);
        w1u[2*n+1] = pk2bf(w1v[2], w1v[3]);
      }
      u16* w1g = (u16*)(ws_b + BOFF_W1) + (size_t)base * 4096 + tid * 16;
      uint4 A, B;
      A.x = w1u[0]; A.y = w1u[1]; A.z = w1u[2]; A.w = w1u[3];
      B.x = w1u[4]; B.y = w1u[5]; B.z = w1u[6]; B.w = w1u[7];
      *(uint4*)&w1g[0] = A;
      *(uint4*)&w1g[8] = B;
    }
    __syncthreads();
  }
  #pragma unroll
  for (int n = 0; n < 4; ++n) {
    #pragma unroll
    for (int reg = 0; reg < 4; ++reg) {
      int i = i0 + reg, j = 16*n + lr;
      atomicAdd(&adj[((size_t)b << 12) + (i << 6) + j], asum[n][reg]);
    }
  }
}

// ---------------- K1b: adjS = bf16(adjnum * msInv) ----------------
__global__ __launch_bounds__(256)
void k_scale(const float* __restrict__ ws_f, char* __restrict__ ws_b) {
  const int b = blockIdx.x, tid = threadIdx.x;
  const float* adj = ws_f + OFF_ADJ + (size_t)b * 4096;
  const float* msI = ws_f + OFF_MS + b * 64;
  u16* as_ = (u16*)(ws_b + BOFF_ADJS) + (size_t)b * 4096;
  #pragma unroll
  for (int k = 0; k < 16; ++k) {
    int idx = k * 256 + tid;
    int i = idx >> 6;
    as_[idx] = f2bf(adj[idx] * msI[i]);
  }
}

// ---------------- K2: prop1+prop2 only (loads hTg/W1p/adjS) ----------------
__global__ __launch_bounds__(256, 4)
void k_main(const float* __restrict__ ws_f, const char* __restrict__ ws_b,
            u16* __restrict__ Hh) {
  __shared__ __align__(16) char smem[36864];
  u16 (*h1L)[72] = (u16 (*)[72])(smem);           // h1T [e][i]
  u16 (*hT)[72]  = (u16 (*)[72])(smem + 9216);    // h^T [e][s]
  u16 (*wA)[72]  = (u16 (*)[72])(smem + 18432);   // w1 [i][j]
  u16 (*adjS)[72]= (u16 (*)[72])(smem + 27648);

  const int tid = threadIdx.x;
  const int t = blockIdx.x, b = blockIdx.y;
  const int w = tid >> 6, l = tid & 63, lr = l & 15, lq = l >> 4, kb = lq * 8;
  const int base = b * 128 + t;
  const int i0 = 16*w + lq*4;

  // prefetch everything (96 B/lane)
  const uint4* ag = (const uint4*)(ws_b + BOFF_ADJS + (size_t)b * 8192);
  uint4 g0 = ag[2*tid], g1 = ag[2*tid + 1];
  const uint4* hp = (const uint4*)((const u16*)(ws_b + BOFF_HT) + (size_t)base * 4096);
  uint4 hv0 = hp[2*tid], hv1 = hp[2*tid + 1];
  const uint4* wp = (const uint4*)((const u16*)(ws_b + BOFF_W1) + (size_t)base * 4096);
  uint4 wp0 = wp[2*tid], wp1 = wp[2*tid + 1];

  { // Pa: stage hT (linear), wA (unpack scatter), adjS
    int r = tid >> 2, c = (tid & 3) * 16;
    *(uint4*)&hT[r][c]     = hv0;
    *(uint4*)&hT[r][c + 8] = hv1;
    u32 q[8] = {wp0.x, wp0.y, wp0.z, wp0.w, wp1.x, wp1.y, wp1.z, wp1.w};
    #pragma unroll
    for (int n = 0; n < 4; ++n) {
      int j = 16*n + lr;
      u32 lo = q[2*n], hi = q[2*n+1];
      wA[i0+0][j] = (u16)lo; wA[i0+1][j] = (u16)(lo >> 16);
      wA[i0+2][j] = (u16)hi; wA[i0+3][j] = (u16)(hi >> 16);
    }
    int idx0 = 2*tid, idx1 = 2*tid + 1;
    *(uint4*)&adjS[idx0 >> 3][(idx0 & 7) * 8] = g0;
    *(uint4*)&adjS[idx1 >> 3][(idx1 & 7) * 8] = g1;
  }
  __syncthreads();

  { // Pc: h1 = relu(w1 @ h) -> h1L
    short8 aw0 = *(const short8*)&wA[16*w + lr][kb];
    short8 aw1 = *(const short8*)&wA[16*w + lr][32 + kb];
    #pragma unroll
    for (int n = 0; n < 4; ++n) {
      f32x4 acc = (f32x4){0.f,0.f,0.f,0.f};
      short8 b0 = *(const short8*)&hT[16*n + lr][kb];
      short8 b1 = *(const short8*)&hT[16*n + lr][32 + kb];
      acc = __builtin_amdgcn_mfma_f32_16x16x32_bf16(aw0, b0, acc, 0, 0, 0);
      acc = __builtin_amdgcn_mfma_f32_16x16x32_bf16(aw1, b1, acc, 0, 0, 0);
      int e = 16*n + lr;
      uint2 pp;
      pp.x = pk2bf(fmaxf(acc[0],0.f), fmaxf(acc[1],0.f));
      pp.y = pk2bf(fmaxf(acc[2],0.f), fmaxf(acc[3],0.f));
      *(uint2*)&h1L[e][i0] = pp;
    }
  }
  __syncthreads();

  { // Pd: w2 = w1 (.) adjS; h2 = relu(w2 @ h1) -> Hh
    int row = 16*w + lr;
    union { short8 v; u16 h[8]; u32 u[4]; } uw0, uw1, ud0, ud1, oa, ob;
    uw0.v = *(const short8*)&wA[row][kb];
    uw1.v = *(const short8*)&wA[row][32 + kb];
    ud0.v = *(const short8*)&adjS[row][kb];
    ud1.v = *(const short8*)&adjS[row][32 + kb];
    #pragma unroll
    for (int k = 0; k < 4; ++k) {
      oa.u[k] = pk2bf(bf2f(uw0.h[2*k])*bf2f(ud0.h[2*k]),
                      bf2f(uw0.h[2*k+1])*bf2f(ud0.h[2*k+1]));
      ob.u[k] = pk2bf(bf2f(uw1.h[2*k])*bf2f(ud1.h[2*k]),
                      bf2f(uw1.h[2*k+1])*bf2f(ud1.h[2*k+1]));
    }
    short8 a20 = oa.v, a21 = ob.v;
    size_t obase = ((size_t)b * 64) * 8192 + (size_t)t * 64;
    #pragma unroll
    for (int n = 0; n < 4; ++n) {
      f32x4 acc = (f32x4){0.f,0.f,0.f,0.f};
      short8 b0 = *(const short8*)&h1L[16*n + lr][kb];
      short8 b1 = *(const short8*)&h1L[16*n + lr][32 + kb];
      acc = __builtin_amdgcn_mfma_f32_16x16x32_bf16(a20, b0, acc, 0, 0, 0);
      acc = __builtin_amdgcn_mfma_f32_16x16x32_bf16(a21, b1, acc, 0, 0, 0);
      int e = 16*n + lr;
      u32 p0 = pk2bf(fmaxf(acc[0],0.f), fmaxf(acc[1],0.f));
      u32 p1 = pk2bf(fmaxf(acc[2],0.f), fmaxf(acc[3],0.f));
      Hh[obase + (size_t)(i0+0) * 8192 + e] = (u16)p0;
      Hh[obase + (size_t)(i0+1) * 8192 + e] = (u16)(p0 >> 16);
      Hh[obase + (size_t)(i0+2) * 8192 + e] = (u16)p1;
      Hh[obase + (size_t)(i0+3) * 8192 + e] = (u16)(p1 >> 16);
    }
  }
}

// ---------------- K3: collapsed temporal attention (512 threads, bf16 PE) ----------------
#define HTP 82

__global__ __launch_bounds__(512)
void k_attn(const char* __restrict__ ws_b, const u16* __restrict__ Hh,
            const float* __restrict__ Wq, const float* __restrict__ bq,
            const float* __restrict__ Wk, const float* __restrict__ bk,
            const float* __restrict__ Ws, const float* __restrict__ bs,
            const float* __restrict__ Wemb, const float* __restrict__ bemb,
            float* __restrict__ out) {
  __shared__ u16 Ht[128][HTP];
  __shared__ u16 peB[128][18];
  __shared__ float wsL[128];
  __shared__ float pA[6][80];
  __shared__ float pK[8][10];
  __shared__ float qvL[80];
  __shared__ float pC[4][128];
  __shared__ float bb[128];
  __shared__ float red[4];
  __shared__ float cstL, sWL;

  const int tid = threadIdx.x;
  const int s = blockIdx.x, b = blockIdx.y;
  const float scale = 0.111803398875f; // 1/sqrt(80)
  const u16* peh = (const u16*)(ws_b + BOFF_PEH);

  const u16* src = Hh + ((size_t)b * 64 + s) * 8192;
  #pragma unroll
  for (int r = 0; r < 2; ++r) {
    int id = r * 512 + tid;
    int tt = id >> 3, c = (id & 7) * 8;
    uint4 q = *(const uint4*)&src[tt * 64 + c];
    u32* dst = (u32*)&Ht[tt][c];
    dst[0] = q.x; dst[1] = q.y; dst[2] = q.z; dst[3] = q.w;
  }
  #pragma unroll
  for (int r = 0; r < 2; ++r) {
    int id = r * 512 + tid;
    u32 pv = ((const u32*)(peh + (size_t)b * 2048))[id];
    *(u32*)&peB[id >> 3][(id & 7) * 2] = pv;
  }
  if (tid < 128) wsL[tid] = Ws[tid];
  __syncthreads();

  if (tid < 480) {
    int d = tid % 80, c = tid / 80;
    int t0 = c * 22, t1 = (t0 + 22 > 128) ? 128 : t0 + 22;
    float a0 = 0.f, a1 = 0.f, a2 = 0.f, a3 = 0.f;
    int t = t0;
    if (d < 64) {
      for (; t + 4 <= t1; t += 4) {
        a0 += wsL[t]   * bf2f(Ht[t][d]);
        a1 += wsL[t+1] * bf2f(Ht[t+1][d]);
        a2 += wsL[t+2] * bf2f(Ht[t+2][d]);
        a3 += wsL[t+3] * bf2f(Ht[t+3][d]);
      }
      for (; t < t1; ++t) a0 += wsL[t] * bf2f(Ht[t][d]);
    } else {
      int k = d - 64;
      for (; t + 4 <= t1; t += 4) {
        a0 += wsL[t]   * bf2f(peB[t][k]);
        a1 += wsL[t+1] * bf2f(peB[t+1][k]);
        a2 += wsL[t+2] * bf2f(peB[t+2][k]);
        a3 += wsL[t+3] * bf2f(peB[t+3][k]);
      }
      for (; t < t1; ++t) a0 += wsL[t] * bf2f(peB[t][k]);
    }
    pA[c][d] = (a0 + a1) + (a2 + a3);
  } else if (tid == 480) {
    float a0 = 0.f, a1 = 0.f, a2 = 0.f, a3 = 0.f;
    for (int t = 0; t < 128; t += 4) {
      a0 += wsL[t]; a1 += wsL[t+1]; a2 += wsL[t+2]; a3 += wsL[t+3];
    }
    sWL = (a0 + a1) + (a2 + a3);
  }
  __syncthreads();

  if (tid < 80) {
    int a = tid % 10, c = tid / 10;
    float a0 = 0.f, a1 = 0.f;
    #pragma unroll
    for (int i = 0; i < 10; i += 2) {
      int d = c * 10 + i;
      float h0 = pA[0][d] + pA[1][d] + pA[2][d] + pA[3][d] + pA[4][d] + pA[5][d];
      float h1 = pA[0][d+1] + pA[1][d+1] + pA[2][d+1] + pA[3][d+1] + pA[4][d+1] + pA[5][d+1];
      a0 += h0 * Wk[d * 10 + a];
      a1 += h1 * Wk[(d+1) * 10 + a];
    }
    pK[c][a] = a0 + a1;
  }
  __syncthreads();

  if (tid <= 80) {
    float kt[10];
    #pragma unroll
    for (int a = 0; a < 10; ++a) {
      float acc = sWL * bk[a];
      #pragma unroll
      for (int c = 0; c < 8; ++c) acc += pK[c][a];
      kt[a] = acc;
    }
    if (tid < 80) {
      float a0 = 0.f, a1 = 0.f;
      #pragma unroll
      for (int a = 0; a < 10; a += 2) {
        a0 += Wq[tid * 10 + a] * kt[a];
        a1 += Wq[tid * 10 + a + 1] * kt[a + 1];
      }
      qvL[tid] = a0 + a1;
    } else {
      float cq = 0.f;
      #pragma unroll
      for (int a = 0; a < 10; ++a) cq += bq[a] * kt[a];
      cstL = scale * cq + bs[0];
    }
  }
  __syncthreads();

  {
    int t = tid & 127, q = tid >> 7;
    float a0 = 0.f, a1 = 0.f, a2 = 0.f, a3 = 0.f;
    const u32* row = (const u32*)&Ht[t][0];
    if (q == 0) {
      #pragma unroll
      for (int i = 0; i < 10; i += 2) {
        u32 p0 = row[i], p1 = row[i+1];
        a0 += bf2f((u16)p0) * qvL[2*i]   + bf2f((u16)(p0 >> 16)) * qvL[2*i+1];
        a1 += bf2f((u16)p1) * qvL[2*i+2] + bf2f((u16)(p1 >> 16)) * qvL[2*i+3];
      }
    } else if (q == 1) {
      #pragma unroll
      for (int i = 10; i < 20; i += 2) {
        u32 p0 = row[i], p1 = row[i+1];
        a0 += bf2f((u16)p0) * qvL[2*i]   + bf2f((u16)(p0 >> 16)) * qvL[2*i+1];
        a1 += bf2f((u16)p1) * qvL[2*i+2] + bf2f((u16)(p1 >> 16)) * qvL[2*i+3];
      }
    } else if (q == 2) {
      #pragma unroll
      for (int i = 20; i < 32; i += 4) {
        u32 p0 = row[i], p1 = row[i+1], p2 = row[i+2], p3 = row[i+3];
        a0 += bf2f((u16)p0) * qvL[2*i]   + bf2f((u16)(p0 >> 16)) * qvL[2*i+1];
        a1 += bf2f((u16)p1) * qvL[2*i+2] + bf2f((u16)(p1 >> 16)) * qvL[2*i+3];
        a2 += bf2f((u16)p2) * qvL[2*i+4] + bf2f((u16)(p2 >> 16)) * qvL[2*i+5];
        a3 += bf2f((u16)p3) * qvL[2*i+6] + bf2f((u16)(p3 >> 16)) * qvL[2*i+7];
      }
    } else {
      #pragma unroll
      for (int k = 0; k < 16; k += 4) {
        a0 += bf2f(peB[t][k])   * qvL[64 + k];
        a1 += bf2f(peB[t][k+1]) * qvL[65 + k];
        a2 += bf2f(peB[t][k+2]) * qvL[66 + k];
        a3 += bf2f(peB[t][k+3]) * qvL[67 + k];
      }
    }
    pC[q][t] = (a0 + a1) + (a2 + a3);
  }
  __syncthreads();

  if (tid < 128) {
    float v = scale * (pC[0][tid] + pC[1][tid] + pC[2][tid] + pC[3][tid]) + cstL;
    bb[tid] = v;
    float mm = v;
    #pragma unroll
    for (int off = 32; off; off >>= 1) mm = fmaxf(mm, __shfl_xor(mm, off));
    if ((tid & 63) == 0) red[tid >> 6] = mm;
  }
  __syncthreads();
  float mx = fmaxf(red[0], red[1]);
  if (tid < 128) {
    float ev = expf(bb[tid] - mx);
    bb[tid] = ev;
    float ss = ev;
    #pragma unroll
    for (int off = 32; off; off >>= 1) ss += __shfl_xor(ss, off);
    if ((tid & 63) == 0) red[2 + (tid >> 6)] = ss;
  }
  __syncthreads();

  if (tid < 480) {
    int d = tid % 80, c = tid / 80;
    int t0 = c * 22, t1 = (t0 + 22 > 128) ? 128 : t0 + 22;
    float a0 = 0.f, a1 = 0.f, a2 = 0.f, a3 = 0.f;
    int t = t0;
    if (d < 64) {
      for (; t + 4 <= t1; t += 4) {
        a0 += bb[t]   * bf2f(Ht[t][d]);
        a1 += bb[t+1] * bf2f(Ht[t+1][d]);
        a2 += bb[t+2] * bf2f(Ht[t+2][d]);
        a3 += bb[t+3] * bf2f(Ht[t+3][d]);
      }
      for (; t < t1; ++t) a0 += bb[t] * bf2f(Ht[t][d]);
    } else {
      int k = d - 64;
      for (; t + 4 <= t1; t += 4) {
        a0 += bb[t]   * bf2f(peB[t][k]);
        a1 += bb[t+1] * bf2f(peB[t+1][k]);
        a2 += bb[t+2] * bf2f(peB[t+2][k]);
        a3 += bb[t+3] * bf2f(peB[t+3][k]);
      }
      for (; t < t1; ++t) a0 += bb[t] * bf2f(peB[t][k]);
    }
    pA[c][d] = (a0 + a1) + (a2 + a3);
  }
  __syncthreads();

  {
    int o = tid & 127, q = tid >> 7;
    int d0 = q * 20;
    float a0 = 0.f, a1 = 0.f, a2 = 0.f, a3 = 0.f;
    #pragma unroll
    for (int i = 0; i < 20; i += 4) {
      int d = d0 + i;
      float h0 = pA[0][d]   + pA[1][d]   + pA[2][d]   + pA[3][d]   + pA[4][d]   + pA[5][d];
      float h1 = pA[0][d+1] + pA[1][d+1] + pA[2][d+1] + pA[3][d+1] + pA[4][d+1] + pA[5][d+1];
      float h2 = pA[0][d+2] + pA[1][d+2] + pA[2][d+2] + pA[3][d+2] + pA[4][d+2] + pA[5][d+2];
      float h3 = pA[0][d+3] + pA[1][d+3] + pA[2][d+3] + pA[3][d+3] + pA[4][d+3] + pA[5][d+3];
      a0 += h0 * Wemb[d * 128 + o];
      a1 += h1 * Wemb[(d+1) * 128 + o];
      a2 += h2 * Wemb[(d+2) * 128 + o];
      a3 += h3 * Wemb[(d+3) * 128 + o];
    }
    pC[q][o] = (a0 + a1) + (a2 + a3);
  }
  __syncthreads();
  if (tid < 128) {
    float rdenom = 1.0f / (red[2] + red[3]);
    out[(((size_t)b * 64 + s) << 7) + tid] =
        bemb[tid] + (pC[0][tid] + pC[1][tid] + pC[2][tid] + pC[3][tid]) * rdenom;
  }
}

extern "C" void kernel_launch(void* const* d_in, const int* in_sizes, int n_in,
                              void* d_out, int out_size, void* d_ws, size_t ws_size,
                              hipStream_t stream) {
  (void)in_sizes; (void)n_in; (void)out_size; (void)ws_size;
  const float* x     = (const float*)d_in[0];
  const float* times = (const float*)d_in[1];
  const float* mask  = (const float*)d_in[2];
  const float* Wobs  = (const float*)d_in[3];
  const float* Wattn = (const float*)d_in[4];
  const float* Wrecv = (const float*)d_in[5];
  const float* brecv = (const float*)d_in[6];
  const float* Wb    = (const float*)d_in[7];
  const float* Wq    = (const float*)d_in[8];
  const float* bq    = (const float*)d_in[9];
  const float* Wk    = (const float*)d_in[10];
  const float* bk    = (const float*)d_in[11];
  const float* Ws    = (const float*)d_in[12];
  const float* bs    = (const float*)d_in[13];
  const float* Wemb  = (const float*)d_in[14];
  const float* bemb  = (const float*)d_in[15];
  float* out = (float*)d_out;
  float* ws_f = (float*)d_ws;
  char* ws_b = (char*)d_ws;
  u16* Hh = (u16*)(ws_b + BOFF_HH);

  k_pre<<<341, 256, 0, stream>>>(times, mask, Wb, Wrecv, brecv, Wattn, ws_f, ws_b);
  k_adj<<<dim3(16, 64), 256, 0, stream>>>(x, mask, Wobs, ws_f, ws_b);
  k_scale<<<64, 256, 0, stream>>>(ws_f, ws_b);
  k_main<<<dim3(128, 64), 256, 0, stream>>>(ws_f, ws_b, Hh);
  k_attn<<<dim3(64, 64), 512, 0, stream>>>(ws_b, Hh, Wq, bq, Wk, bk, Ws, bs, Wemb, bemb, out);
}